// Round 17
// baseline (175.134 us; speedup 1.0000x reference)
//
#include <hip/hip_runtime.h>
#include <hip/hip_bf16.h>

#define TLEN 16000
#define NPSI 36
#define NBATCH 64
#define NOUT 250
#define NCH 37
#define DHALF 176            // Gaussian lowpass half-width (6.05 sigma, sigma_t=29.1)
#define KMAX 8000
#define TWO_PI 6.283185307179586

__device__ __forceinline__ int brev7(int q){ return (int)(__brev((unsigned)q) >> 25); }
__device__ __forceinline__ int drev125(int p){
    return (p % 5) * 25 + ((p / 5) % 5) * 5 + (p / 25);
}

// ---- K1a (split): radix-5 over n1 for 32 n2-rows + W16000 twiddle --------
__global__ __launch_bounds__(256) void k_ffta(const float* __restrict__ x,
                                              float2* __restrict__ Gtmp){
    __shared__ float xr[32 * 126], xi[32 * 126];
    __shared__ float w125r[125], w125i[125];  // e^{-2pi j/125}
    __shared__ float w16r[125],  w16i[125];   // e^{-2pi j/16000}
    __shared__ float w128r[128], w128i[128];  // e^{-2pi j/128}
    const int b = blockIdx.x >> 2, g = blockIdx.x & 3, row0 = 32 * g;
    const int tid = threadIdx.x;

    for (int j = tid; j < 125; j += 256){
        double a = -TWO_PI * (double)j / 125.0;
        w125r[j] = (float)cos(a); w125i[j] = (float)sin(a);
        double a2 = -TWO_PI * (double)j / 16000.0;
        w16r[j] = (float)cos(a2); w16i[j] = (float)sin(a2);
    }
    for (int j = tid; j < 128; j += 256){
        double a = -TWO_PI * (double)j / 128.0;
        w128r[j] = (float)cos(a); w128i[j] = (float)sin(a);
    }
    for (int i = tid; i < 32 * 125; i += 256){
        int n1 = i >> 5, lr = i & 31;
        xr[lr * 126 + n1] = x[b * TLEN + 128 * n1 + row0 + lr];
        xi[lr * 126 + n1] = 0.0f;
    }
    int f = 1;
    for (int s = 25; s >= 1; s /= 5, f *= 5){
        __syncthreads();
        for (int task = tid; task < 25 * 32; task += 256){
            int u = task >> 5, lr = task & 31;
            int blk = u / s, m = u - blk * s;
            int base = lr * 126 + blk * 5 * s + m;
            float vr[5], vi[5];
            #pragma unroll
            for (int r = 0; r < 5; ++r){ vr[r] = xr[base + r * s]; vi[r] = xi[base + r * s]; }
            #pragma unroll
            for (int q = 0; q < 5; ++q){
                float cr = vr[0], ci = vi[0];
                #pragma unroll
                for (int r = 1; r < 5; ++r){
                    int w5 = 25 * ((q * r) % 5);
                    float wr = w125r[w5], wi = w125i[w5];
                    cr += vr[r] * wr - vi[r] * wi;
                    ci += vr[r] * wi + vi[r] * wr;
                }
                int jt = (m * q * f) % 125;
                float tr = w125r[jt], ti = w125i[jt];
                xr[base + q * s] = cr * tr - ci * ti;
                xi[base + q * s] = cr * ti + ci * tr;
            }
        }
    }
    __syncthreads();
    for (int i = tid; i < 125 * 32; i += 256){
        int p = i >> 5, lr = i & 31;
        int n2 = row0 + lr;
        int m = drev125(p);
        int a = m * n2;
        int qq = a / 125, rr = a - qq * 125;
        float tr = w16r[rr] * w128r[qq] - w16i[rr] * w128i[qq];
        float ti = w16r[rr] * w128i[qq] + w16i[rr] * w128r[qq];
        float ar = xr[lr * 126 + p], ai = xi[lr * 126 + p];
        Gtmp[((size_t)b * 125 + p) * 128 + n2] =
            make_float2(ar * tr - ai * ti, ar * ti + ai * tr);
    }
}

// ---- K1b (split): radix-2 over n2 for 25 phys cols; emit k<8000 ----------
__global__ __launch_bounds__(256) void k_fftb(const float2* __restrict__ Gtmp,
                                              float2* __restrict__ Xf){
    __shared__ float gr[128 * 26], gi[128 * 26];
    __shared__ float w128r[128], w128i[128];
    const int b = blockIdx.x / 5, p0 = (blockIdx.x % 5) * 25;
    const int tid = threadIdx.x;
    for (int j = tid; j < 128; j += 256){
        double a = -TWO_PI * (double)j / 128.0;
        w128r[j] = (float)cos(a); w128i[j] = (float)sin(a);
    }
    for (int i = tid; i < 25 * 128; i += 256){
        int ml = i >> 7, n2 = i & 127;
        float2 v = Gtmp[((size_t)b * 125 + p0 + ml) * 128 + n2];
        gr[n2 * 26 + ml] = v.x; gi[n2 * 26 + ml] = v.y;
    }
    for (int span = 64; span >= 1; span >>= 1){
        __syncthreads();
        for (int idx = tid; idx < 1600; idx += 256){
            int u = idx / 25, ml = idx - u * 25;
            int blkq = u / span, mm = u % span;
            int i0 = (blkq * 2 * span + mm) * 26 + ml, i1 = i0 + span * 26;
            float ar = gr[i0], ai = gi[i0], br = gr[i1], bi = gi[i1];
            gr[i0] = ar + br; gi[i0] = ai + bi;
            float dr = ar - br, di = ai - bi;
            int jt = mm * (64 / span);
            gr[i1] = dr * w128r[jt] - di * w128i[jt];
            gi[i1] = dr * w128i[jt] + di * w128r[jt];
        }
    }
    __syncthreads();
    for (int idx = tid; idx < 1600; idx += 256){
        int u = idx / 25, ml = idx - u * 25;
        int ad = (2 * u) * 26 + ml;
        int k = drev125(p0 + ml) + 125 * brev7(2 * u);
        Xf[(size_t)b * KMAX + k] = make_float2(gr[ad], gi[ad]);
    }
}

// ---- env body, templated on thread count NT ------------------------------
template<int P5, int LQ, int NT>
__device__ __forceinline__ void env_body(const float2* __restrict__ Xfb,
                                         float* __restrict__ Schan,
                                         int fi, int b, int tid,
                                         float* Br, float* Bi,
                                         float* wPr, float* wPi,
                                         float* wNr, float* wNi,
                                         float* wQr, float* wQi,
                                         float* w5tr, float* w5ti,
                                         float* hfull, int* drevT, float* sred){
    constexpr int Q = 1 << LQ;
    constexpr int N = P5 * Q;
    constexpr int D = TLEN / N;
    constexpr int S1 = P5 / 5;
    constexpr int NIT = (N + NT - 1) / NT;
    constexpr int TSPL = (NT >= 1024) ? 4 : 2;

    const double xi_d = 0.35 * exp2(-(double)fi / 6.0);
    const double r_d  = exp2(1.0 / 6.0);
    const double sig_d = xi_d * (r_d - 1.0) / (r_d + 1.0);
    const float xi = (float)xi_d;
    const float centerT = (float)(xi_d * (double)TLEN);
    const float sigT = (float)(sig_d * (double)TLEN);
    int klo = (int)floorf(centerT - 5.0f * sigT); if (klo < 1) klo = 1;
    int khi = (int)ceilf(centerT + 5.0f * sigT);  if (khi > KMAX - 1) khi = KMAX - 1;
    const float inv2s2 = (float)(1.0 / (2.0 * sig_d * sig_d));

    for (int j = tid; j < P5; j += NT){
        double a = TWO_PI * (double)j / (double)P5;
        wPr[j] = (float)cos(a); wPi[j] = (float)sin(a);
        double a2 = TWO_PI * (double)j / (double)N;
        wNr[j] = (float)cos(a2); wNi[j] = (float)sin(a2);
        drevT[j] = (P5 == 125) ? drev125(j) : ((j % 5) * 5 + j / 5);
    }
    for (int j = tid; j < Q; j += NT){
        double a = TWO_PI * (double)j / (double)Q;
        wQr[j] = (float)cos(a); wQi[j] = (float)sin(a);
    }
    for (int j = tid; j < 25; j += NT){
        double a = TWO_PI * (double)(((j / 5) * (j % 5)) % 5) / 5.0;   // e^{+2pi(qr%5)/5}
        w5tr[j] = (float)cos(a); w5ti[j] = (float)sin(a);
    }
    for (int j = tid; j <= 2 * DHALF; j += NT){
        double st = 1.0 / (TWO_PI * (0.35 / 64.0));
        double dd = (double)(j - DHALF);
        hfull[j] = (float)((0.35 / 64.0) * sqrt(TWO_PI) * exp(-0.5 * dd * dd / (st * st)));
    }
    __syncthreads();
    // ---- radix-5 stage 1 over j, FUSED with psi-weighted global init -----
    for (int task = tid; task < S1 * Q; task += NT){
        int m = task >> LQ, k2 = task & (Q - 1);
        float vr[5], vi[5];
        #pragma unroll
        for (int r = 0; r < 5; ++r){
            int gk = k2 + ((m + r * S1) << LQ);
            float ur = 0.0f, ui = 0.0f;
            if (gk >= klo && gk <= khi){
                float fr = (float)gk * (1.0f / (float)TLEN);
                float d = fr - xi;
                float p = __expf(-d * d * inv2s2) * (1.0f / (float)TLEN);
                float2 Xv = Xfb[gk];
                ur = Xv.x * p; ui = Xv.y * p;
            }
            vr[r] = ur; vi[r] = ui;
        }
        int base = m * Q + k2;
        #pragma unroll
        for (int q = 0; q < 5; ++q){
            float cr = vr[0], ci = vi[0];
            #pragma unroll
            for (int r = 1; r < 5; ++r){
                float wr = w5tr[q * 5 + r], wi = w5ti[q * 5 + r];
                cr += vr[r] * wr - vi[r] * wi;
                ci += vr[r] * wi + vi[r] * wr;
            }
            int jt = m * q;                   // f = 1
            float tr = wPr[jt], ti = wPi[jt];
            Br[base + q * S1 * Q] = cr * tr - ci * ti;
            Bi[base + q * S1 * Q] = cr * ti + ci * tr;
        }
    }
    // ---- middle radix-5 stage (P5=125 only): s=5, f=5 --------------------
    if (P5 == 125){
        __syncthreads();
        for (int task = tid; task < 25 * Q; task += NT){
            int u = task >> LQ, k2 = task & (Q - 1);
            int blk = u / 5, m = u - blk * 5;
            int base = (blk * 25 + m) * Q + k2;
            float vr[5], vi[5];
            #pragma unroll
            for (int r = 0; r < 5; ++r){ vr[r] = Br[base + r * 5 * Q]; vi[r] = Bi[base + r * 5 * Q]; }
            #pragma unroll
            for (int q = 0; q < 5; ++q){
                float cr = vr[0], ci = vi[0];
                #pragma unroll
                for (int r = 1; r < 5; ++r){
                    float wr = w5tr[q * 5 + r], wi = w5ti[q * 5 + r];
                    cr += vr[r] * wr - vi[r] * wi;
                    ci += vr[r] * wi + vi[r] * wr;
                }
                int jt = m * q * 5;           // < 125
                float tr = wPr[jt], ti = wPi[jt];
                Br[base + q * 5 * Q] = cr * tr - ci * ti;
                Bi[base + q * 5 * Q] = cr * ti + ci * tr;
            }
        }
    }
    // ---- final radix-5 stage fused with W_N^{+k2 n1} output twiddle ------
    __syncthreads();
    for (int task = tid; task < S1 * Q; task += NT){
        int u = task >> LQ, k2 = task & (Q - 1);
        int base = (u * 5) * Q + k2;
        float vr[5], vi[5];
        #pragma unroll
        for (int r = 0; r < 5; ++r){ vr[r] = Br[base + r * Q]; vi[r] = Bi[base + r * Q]; }
        #pragma unroll
        for (int q = 0; q < 5; ++q){
            float cr = vr[0], ci = vi[0];
            #pragma unroll
            for (int r = 1; r < 5; ++r){
                float wr = w5tr[q * 5 + r], wi = w5ti[q * 5 + r];
                cr += vr[r] * wr - vi[r] * wi;
                ci += vr[r] * wi + vi[r] * wr;
            }
            int n1 = drevT[5 * u + q];
            int a = k2 * n1;                  // < N = P5*qq + rr
            int qq = a / P5, rr = a - qq * P5;
            float tr = wQr[qq] * wNr[rr] - wQi[qq] * wNi[rr];
            float ti = wQr[qq] * wNi[rr] + wQi[qq] * wNr[rr];
            Br[base + q * Q] = cr * tr - ci * ti;
            Bi[base + q * Q] = cr * ti + ci * tr;
        }
    }
    // ---- radix-4 passes over k2 (fused radix-2 pairs, plus sign) ---------
    #pragma unroll
    for (int pass = 0; pass < LQ / 2; ++pass){
        const int Sp = Q >> (1 + 2 * pass);
        const int half = Sp >> 1;
        __syncthreads();
        for (int task = tid; task < P5 * (Q / 4); task += NT){
            int prow = task / (Q / 4), v = task & (Q / 4 - 1);
            int blkq = v / half, m = v - blkq * half;
            int base = prow * Q + blkq * 2 * Sp + m;
            float Ar = Br[base],           Ai = Bi[base];
            float B2r = Br[base + half],   B2i = Bi[base + half];
            float Cr = Br[base + Sp],      Ci = Bi[base + Sp];
            float D2r = Br[base + Sp + half], D2i = Bi[base + Sp + half];
            int jt1 = m * ((Q / 2) / Sp);
            float w1r = wQr[jt1], w1i = wQi[jt1];
            float w2r = wQr[2 * jt1], w2i = wQi[2 * jt1];
            float A1r = Ar + Cr, A1i = Ai + Ci;
            float t1r = Ar - Cr, t1i = Ai - Ci;
            float C1r = t1r * w1r - t1i * w1i, C1i = t1r * w1i + t1i * w1r;
            float B1r = B2r + D2r, B1i = B2i + D2i;
            float t2r = B2r - D2r, t2i = B2i - D2i;
            float t3r = -t2i, t3i = t2r;
            float D1r = t3r * w1r - t3i * w1i, D1i = t3r * w1i + t3i * w1r;
            Br[base] = A1r + B1r;  Bi[base] = A1i + B1i;
            float u1r = A1r - B1r, u1i = A1i - B1i;
            Br[base + half] = u1r * w2r - u1i * w2i;
            Bi[base + half] = u1r * w2i + u1i * w2r;
            Br[base + Sp] = C1r + D1r;  Bi[base + Sp] = C1i + D1i;
            float u2r = C1r - D1r, u2i = C1i - D1i;
            Br[base + Sp + half] = u2r * w2r - u2i * w2i;
            Bi[base + Sp + half] = u2r * w2i + u2i * w2r;
        }
    }
    if (LQ & 1){                              // leftover span=1 radix-2 (W=1)
        __syncthreads();
        for (int idx = tid; idx < P5 * (Q / 2); idx += NT){
            int p = idx / (Q / 2), u = idx - p * (Q / 2);
            int i0 = p * Q + 2 * u, i1 = i0 + 1;
            float ar = Br[i0], ai = Bi[i0], br2 = Br[i1], bi2 = Bi[i1];
            Br[i0] = ar + br2; Bi[i0] = ai + bi2;
            Br[i1] = ar - br2; Bi[i1] = ai - bi2;
        }
    }
    __syncthreads();
    // ---- |z| -> registers (static idx), padded-linear scatter to Bi ------
    float magv[NIT];
    #pragma unroll
    for (int i = 0; i < NIT; ++i){
        int idx = tid + NT * i;
        if (idx < N){
            float vr = Br[idx], vi = Bi[idx];
            magv[i] = sqrtf(vr * vr + vi * vi);
        }
    }
    __syncthreads();
    #pragma unroll
    for (int i = 0; i < NIT; ++i){
        int idx = tid + NT * i;
        if (idx < N){
            int p = idx >> LQ, u = idx & (Q - 1);
            int s2 = (int)(__brev((unsigned)u) >> (32 - LQ));
            int np = drevT[p] + P5 * s2;
            Bi[np + (np >> 5)] = magv[i];
        }
    }
    __syncthreads();
    // ---- conv: S1[t] = D * sum_n phi(64t - Dn) Mag[n], TSPL-way split ----
    float acc = 0.0f;
    if (tid < 250 * TSPL){
        int t = tid - 250 * (tid / 250);
        int q = tid / 250;
        int m0 = 64 * t;
        int lo = m0 - DHALF;
        int nlo = (lo >= 0) ? ((lo + D - 1) / D) : -((-lo) / D);
        int nhi = (m0 + DHALF) / D;
        int n = nlo + q;
        if (n <= nhi){
            int np = n % N; if (np < 0) np += N;
            int d = m0 - D * n + DHALF;
            for (; n <= nhi; n += TSPL){
                acc += hfull[d] * Bi[np + (np >> 5)];
                d -= TSPL * D;
                np += TSPL; if (np >= N) np -= N;
            }
        }
        sred[tid] = acc;
    }
    __syncthreads();
    if (tid < 250){
        float s = sred[tid] + sred[tid + 250];
        if (TSPL == 4) s += sred[tid + 500] + sred[tid + 750];
        Schan[(b * NCH + 1 + fi) * NOUT + tid] = s * (float)D;
    }
}

// ---- K2: all 36 channels + S0, single dispatch, 1024 threads/block -------
// LDS 72.9 KB -> 2 blocks/CU; 2 x 16 waves = 32 waves/CU (full occupancy).
__global__ __launch_bounds__(1024, 4) void k_env_all(const float* __restrict__ x,
                                                     const float2* __restrict__ Xf,
                                                     float* __restrict__ Schan){
    __shared__ float Br[8000];
    __shared__ float Bi[8256];                 // complex plane, then padded Mag
    __shared__ float wPr[125], wPi[125];
    __shared__ float wNr[125], wNi[125];
    __shared__ float wQr[128], wQi[128];
    __shared__ float w5tr[25], w5ti[25];
    __shared__ float hfull[2 * DHALF + 1];
    __shared__ int   drevT[125];
    __shared__ float sred[1000];

    const int bi = blockIdx.x;
    const int tid = threadIdx.x;
    if (bi < 448){                         // N=8000, D=2,  fi 0-6
        int fi = bi >> 6, b = bi & 63;
        env_body<125, 6, 1024>(Xf + (size_t)b * KMAX, Schan, fi, b, tid, Br, Bi,
                               wPr, wPi, wNr, wNi, wQr, wQi, w5tr, w5ti, hfull, drevT, sred);
    } else if (bi < 640){                  // N=4000, D=4,  fi 7-9
        int t = bi - 448;
        int fi = 7 + (t >> 6), b = t & 63;
        env_body<125, 5, 1024>(Xf + (size_t)b * KMAX, Schan, fi, b, tid, Br, Bi,
                               wPr, wPi, wNr, wNi, wQr, wQi, w5tr, w5ti, hfull, drevT, sred);
    } else if (bi < 1088){                 // N=3200, D=5,  fi 10-16
        int t = bi - 640;
        int fi = 10 + (t >> 6), b = t & 63;
        env_body<25, 7, 1024>(Xf + (size_t)b * KMAX, Schan, fi, b, tid, Br, Bi,
                              wPr, wPi, wNr, wNi, wQr, wQi, w5tr, w5ti, hfull, drevT, sred);
    } else if (bi < 1408){                 // N=2000, D=8,  fi 17-21
        int t = bi - 1088;
        int fi = 17 + (t >> 6), b = t & 63;
        env_body<125, 4, 1024>(Xf + (size_t)b * KMAX, Schan, fi, b, tid, Br, Bi,
                               wPr, wPi, wNr, wNi, wQr, wQi, w5tr, w5ti, hfull, drevT, sred);
    } else if (bi < 2304){                 // N=1600, D=10, fi 22-35
        int t = bi - 1408;
        int fi = 22 + (t >> 6), b = t & 63;
        env_body<25, 6, 1024>(Xf + (size_t)b * KMAX, Schan, fi, b, tid, Br, Bi,
                              wPr, wPi, wNr, wNi, wQr, wQi, w5tr, w5ti, hfull, drevT, sred);
    } else {                               // S0 channel, one block per batch
        int b = bi - 2304;
        const float* xb = x + (size_t)b * TLEN;
        for (int j = tid; j <= 2 * DHALF; j += 1024){
            double st = 1.0 / (TWO_PI * (0.35 / 64.0));
            double dd = (double)(j - DHALF);
            hfull[j] = (float)((0.35 / 64.0) * sqrt(TWO_PI) * exp(-0.5 * dd * dd / (st * st)));
        }
        __syncthreads();
        float acc = 0.0f;
        if (tid < 1000){
            int t = tid - 250 * (tid / 250);
            int q = tid / 250;
            int m0 = 64 * t;
            for (int j = q; j <= 2 * DHALF; j += 4){
                int n = m0 - DHALF + j;
                if (n < 0) n += TLEN; else if (n >= TLEN) n -= TLEN;
                acc += hfull[j] * xb[n];
            }
            sred[tid] = acc;
        }
        __syncthreads();
        if (tid < 250)
            Schan[(b * NCH + 0) * NOUT + tid] =
                sred[tid] + sred[tid + 250] + sred[tid + 500] + sred[tid + 750];
    }
}

// ---- K4: channel-group means -> f32 --------------------------------------
__global__ __launch_bounds__(256) void k_reduce(const float* __restrict__ Schan,
                                                float* __restrict__ out){
    int o = blockIdx.x * 256 + threadIdx.x;
    if (o >= NBATCH * 3 * NOUT) return;
    int b = o / (3 * NOUT);
    int rem = o - b * 3 * NOUT;
    int g = rem / NOUT;
    int t = rem - g * NOUT;
    int c0 = (g == 0) ? 0 : (g == 1 ? 12 : 24);
    int c1 = (g == 0) ? 12 : (g == 1 ? 24 : 37);
    float s = 0.0f;
    for (int c = c0; c < c1; ++c) s += Schan[(b * NCH + c) * NOUT + t];
    out[o] = s / (float)(c1 - c0);
}

__global__ void k_fill_f32(float* out, int n, float v){
    int i = blockIdx.x * 256 + threadIdx.x;
    if (i < n) out[i] = v;
}

extern "C" void kernel_launch(void* const* d_in, const int* in_sizes, int n_in,
                              void* d_out, int out_size, void* d_ws, size_t ws_size,
                              hipStream_t stream) {
    const float* x = (const float*)d_in[0];
    float* out = (float*)d_out;
    const size_t xf_bytes = (size_t)NBATCH * KMAX * sizeof(float2);          // 4.10 MB
    const size_t schan_bytes = (size_t)NBATCH * NCH * NOUT * sizeof(float);  // 2.37 MB
    const size_t gtmp_bytes = (size_t)NBATCH * 16000 * sizeof(float2);       // 8.19 MB
    if (ws_size < xf_bytes + schan_bytes + gtmp_bytes){
        k_fill_f32<<<(out_size + 255) / 256, 256, 0, stream>>>(out, out_size, 800.0f);
        return;
    }
    float2* Xf = (float2*)d_ws;
    float* Schan = (float*)((char*)d_ws + xf_bytes);
    float2* Gtmp = (float2*)((char*)d_ws + xf_bytes + schan_bytes);

    k_ffta<<<NBATCH * 4, 256, 0, stream>>>(x, Gtmp);
    k_fftb<<<NBATCH * 5, 256, 0, stream>>>(Gtmp, Xf);
    k_env_all<<<2368, 1024, 0, stream>>>(x, Xf, Schan);
    k_reduce<<<(NBATCH * 3 * NOUT + 255) / 256, 256, 0, stream>>>(Schan, out);
}

// Round 18
// 151.686 us; speedup vs baseline: 1.1546x; 1.1546x over previous
//
#include <hip/hip_runtime.h>
#include <hip/hip_bf16.h>

#define TLEN 16000
#define NPSI 36
#define NBATCH 64
#define NOUT 250
#define NCH 37
#define DHALF 176            // Gaussian lowpass half-width (6.05 sigma, sigma_t=29.1)
#define KMAX 8000
#define TWO_PI 6.283185307179586

__device__ __forceinline__ int brev7(int q){ return (int)(__brev((unsigned)q) >> 25); }
__device__ __forceinline__ int drev125(int p){
    return (p % 5) * 25 + ((p / 5) % 5) * 5 + (p / 25);
}

// ---- K1a (split): radix-5 over n1 for 32 n2-rows + W16000 twiddle --------
__global__ __launch_bounds__(256) void k_ffta(const float* __restrict__ x,
                                              float2* __restrict__ Gtmp){
    __shared__ float xr[32 * 126], xi[32 * 126];
    __shared__ float w125r[125], w125i[125];  // e^{-2pi j/125}
    __shared__ float w16r[125],  w16i[125];   // e^{-2pi j/16000}
    __shared__ float w128r[128], w128i[128];  // e^{-2pi j/128}
    const int b = blockIdx.x >> 2, g = blockIdx.x & 3, row0 = 32 * g;
    const int tid = threadIdx.x;

    for (int j = tid; j < 125; j += 256){
        double a = -TWO_PI * (double)j / 125.0;
        w125r[j] = (float)cos(a); w125i[j] = (float)sin(a);
        double a2 = -TWO_PI * (double)j / 16000.0;
        w16r[j] = (float)cos(a2); w16i[j] = (float)sin(a2);
    }
    for (int j = tid; j < 128; j += 256){
        double a = -TWO_PI * (double)j / 128.0;
        w128r[j] = (float)cos(a); w128i[j] = (float)sin(a);
    }
    for (int i = tid; i < 32 * 125; i += 256){
        int n1 = i >> 5, lr = i & 31;
        xr[lr * 126 + n1] = x[b * TLEN + 128 * n1 + row0 + lr];
        xi[lr * 126 + n1] = 0.0f;
    }
    int f = 1;
    for (int s = 25; s >= 1; s /= 5, f *= 5){
        __syncthreads();
        for (int task = tid; task < 25 * 32; task += 256){
            int u = task >> 5, lr = task & 31;
            int blk = u / s, m = u - blk * s;
            int base = lr * 126 + blk * 5 * s + m;
            float vr[5], vi[5];
            #pragma unroll
            for (int r = 0; r < 5; ++r){ vr[r] = xr[base + r * s]; vi[r] = xi[base + r * s]; }
            #pragma unroll
            for (int q = 0; q < 5; ++q){
                float cr = vr[0], ci = vi[0];
                #pragma unroll
                for (int r = 1; r < 5; ++r){
                    int w5 = 25 * ((q * r) % 5);
                    float wr = w125r[w5], wi = w125i[w5];
                    cr += vr[r] * wr - vi[r] * wi;
                    ci += vr[r] * wi + vi[r] * wr;
                }
                int jt = (m * q * f) % 125;
                float tr = w125r[jt], ti = w125i[jt];
                xr[base + q * s] = cr * tr - ci * ti;
                xi[base + q * s] = cr * ti + ci * tr;
            }
        }
    }
    __syncthreads();
    for (int i = tid; i < 125 * 32; i += 256){
        int p = i >> 5, lr = i & 31;
        int n2 = row0 + lr;
        int m = drev125(p);
        int a = m * n2;
        int qq = a / 125, rr = a - qq * 125;
        float tr = w16r[rr] * w128r[qq] - w16i[rr] * w128i[qq];
        float ti = w16r[rr] * w128i[qq] + w16i[rr] * w128r[qq];
        float ar = xr[lr * 126 + p], ai = xi[lr * 126 + p];
        Gtmp[((size_t)b * 125 + p) * 128 + n2] =
            make_float2(ar * tr - ai * ti, ar * ti + ai * tr);
    }
}

// ---- K1b (split): radix-2 over n2 for 25 phys cols; emit k<8000 ----------
__global__ __launch_bounds__(256) void k_fftb(const float2* __restrict__ Gtmp,
                                              float2* __restrict__ Xf){
    __shared__ float gr[128 * 26], gi[128 * 26];
    __shared__ float w128r[128], w128i[128];
    const int b = blockIdx.x / 5, p0 = (blockIdx.x % 5) * 25;
    const int tid = threadIdx.x;
    for (int j = tid; j < 128; j += 256){
        double a = -TWO_PI * (double)j / 128.0;
        w128r[j] = (float)cos(a); w128i[j] = (float)sin(a);
    }
    for (int i = tid; i < 25 * 128; i += 256){
        int ml = i >> 7, n2 = i & 127;
        float2 v = Gtmp[((size_t)b * 125 + p0 + ml) * 128 + n2];
        gr[n2 * 26 + ml] = v.x; gi[n2 * 26 + ml] = v.y;
    }
    for (int span = 64; span >= 1; span >>= 1){
        __syncthreads();
        for (int idx = tid; idx < 1600; idx += 256){
            int u = idx / 25, ml = idx - u * 25;
            int blkq = u / span, mm = u % span;
            int i0 = (blkq * 2 * span + mm) * 26 + ml, i1 = i0 + span * 26;
            float ar = gr[i0], ai = gi[i0], br = gr[i1], bi = gi[i1];
            gr[i0] = ar + br; gi[i0] = ai + bi;
            float dr = ar - br, di = ai - bi;
            int jt = mm * (64 / span);
            gr[i1] = dr * w128r[jt] - di * w128i[jt];
            gi[i1] = dr * w128i[jt] + di * w128r[jt];
        }
    }
    __syncthreads();
    for (int idx = tid; idx < 1600; idx += 256){
        int u = idx / 25, ml = idx - u * 25;
        int ad = (2 * u) * 26 + ml;
        int k = drev125(p0 + ml) + 125 * brev7(2 * u);
        Xf[(size_t)b * KMAX + k] = make_float2(gr[ad], gi[ad]);
    }
}

// ---- env body: radix-5 stages in LDS, then WAVE-LOCAL shuffle FFT over k2
// (register-resident, no barriers) + direct |z| write, conflict-free conv --
template<int P5, int LQ>
__device__ __forceinline__ void env_body(const float2* __restrict__ Xfb,
                                         float* __restrict__ Schan,
                                         int fi, int b, int tid,
                                         float* Br, float* Bi,
                                         float* wPr, float* wPi,
                                         float* wNr, float* wNi,
                                         float* wQr, float* wQi,
                                         float* w5tr, float* w5ti,
                                         float* hfull, int* drevT, float* sred){
    constexpr int Q = 1 << LQ;
    constexpr int N = P5 * Q;
    constexpr int D = TLEN / N;
    constexpr int S1 = P5 / 5;
    constexpr int GROUPW = (Q > 64) ? 64 : Q;     // lanes per row-group
    constexpr int E = (Q > 64) ? 2 : 1;           // elements per lane
    constexpr int RPP = 64 / GROUPW;              // rows per wave-pass
    constexpr int NPASS = (P5 + 8 * RPP - 1) / (8 * RPP);

    const double xi_d = 0.35 * exp2(-(double)fi / 6.0);
    const double r_d  = exp2(1.0 / 6.0);
    const double sig_d = xi_d * (r_d - 1.0) / (r_d + 1.0);
    const float xi = (float)xi_d;
    const float centerT = (float)(xi_d * (double)TLEN);
    const float sigT = (float)(sig_d * (double)TLEN);
    int klo = (int)floorf(centerT - 5.0f * sigT); if (klo < 1) klo = 1;
    int khi = (int)ceilf(centerT + 5.0f * sigT);  if (khi > KMAX - 1) khi = KMAX - 1;
    const float inv2s2 = (float)(1.0 / (2.0 * sig_d * sig_d));

    for (int j = tid; j < P5; j += 512){
        double a = TWO_PI * (double)j / (double)P5;
        wPr[j] = (float)cos(a); wPi[j] = (float)sin(a);
        double a2 = TWO_PI * (double)j / (double)N;
        wNr[j] = (float)cos(a2); wNi[j] = (float)sin(a2);
        drevT[j] = (P5 == 125) ? drev125(j) : ((j % 5) * 5 + j / 5);
    }
    for (int j = tid; j < Q; j += 512){
        double a = TWO_PI * (double)j / (double)Q;
        wQr[j] = (float)cos(a); wQi[j] = (float)sin(a);
    }
    for (int j = tid; j < 25; j += 512){
        double a = TWO_PI * (double)(((j / 5) * (j % 5)) % 5) / 5.0;   // e^{+2pi(qr%5)/5}
        w5tr[j] = (float)cos(a); w5ti[j] = (float)sin(a);
    }
    for (int j = tid; j <= 2 * DHALF; j += 512){
        double st = 1.0 / (TWO_PI * (0.35 / 64.0));
        double dd = (double)(j - DHALF);
        hfull[j] = (float)((0.35 / 64.0) * sqrt(TWO_PI) * exp(-0.5 * dd * dd / (st * st)));
    }
    __syncthreads();
    // ---- radix-5 stage 1 over j, FUSED with psi-weighted global init -----
    for (int task = tid; task < S1 * Q; task += 512){
        int m = task >> LQ, k2 = task & (Q - 1);
        float vr[5], vi[5];
        #pragma unroll
        for (int r = 0; r < 5; ++r){
            int gk = k2 + ((m + r * S1) << LQ);
            float ur = 0.0f, ui = 0.0f;
            if (gk >= klo && gk <= khi){
                float fr = (float)gk * (1.0f / (float)TLEN);
                float d = fr - xi;
                float p = __expf(-d * d * inv2s2) * (1.0f / (float)TLEN);
                float2 Xv = Xfb[gk];
                ur = Xv.x * p; ui = Xv.y * p;
            }
            vr[r] = ur; vi[r] = ui;
        }
        int base = m * Q + k2;
        #pragma unroll
        for (int q = 0; q < 5; ++q){
            float cr = vr[0], ci = vi[0];
            #pragma unroll
            for (int r = 1; r < 5; ++r){
                float wr = w5tr[q * 5 + r], wi = w5ti[q * 5 + r];
                cr += vr[r] * wr - vi[r] * wi;
                ci += vr[r] * wi + vi[r] * wr;
            }
            int jt = m * q;                   // f = 1
            float tr = wPr[jt], ti = wPi[jt];
            Br[base + q * S1 * Q] = cr * tr - ci * ti;
            Bi[base + q * S1 * Q] = cr * ti + ci * tr;
        }
    }
    // ---- middle radix-5 stage (P5=125 only): s=5, f=5 --------------------
    if (P5 == 125){
        __syncthreads();
        for (int task = tid; task < 25 * Q; task += 512){
            int u = task >> LQ, k2 = task & (Q - 1);
            int blk = u / 5, m = u - blk * 5;
            int base = (blk * 25 + m) * Q + k2;
            float vr[5], vi[5];
            #pragma unroll
            for (int r = 0; r < 5; ++r){ vr[r] = Br[base + r * 5 * Q]; vi[r] = Bi[base + r * 5 * Q]; }
            #pragma unroll
            for (int q = 0; q < 5; ++q){
                float cr = vr[0], ci = vi[0];
                #pragma unroll
                for (int r = 1; r < 5; ++r){
                    float wr = w5tr[q * 5 + r], wi = w5ti[q * 5 + r];
                    cr += vr[r] * wr - vi[r] * wi;
                    ci += vr[r] * wi + vi[r] * wr;
                }
                int jt = m * q * 5;           // < 125
                float tr = wPr[jt], ti = wPi[jt];
                Br[base + q * 5 * Q] = cr * tr - ci * ti;
                Bi[base + q * 5 * Q] = cr * ti + ci * tr;
            }
        }
    }
    // ---- final radix-5 stage fused with W_N^{+k2 n1} output twiddle ------
    __syncthreads();
    for (int task = tid; task < S1 * Q; task += 512){
        int u = task >> LQ, k2 = task & (Q - 1);
        int base = (u * 5) * Q + k2;
        float vr[5], vi[5];
        #pragma unroll
        for (int r = 0; r < 5; ++r){ vr[r] = Br[base + r * Q]; vi[r] = Bi[base + r * Q]; }
        #pragma unroll
        for (int q = 0; q < 5; ++q){
            float cr = vr[0], ci = vi[0];
            #pragma unroll
            for (int r = 1; r < 5; ++r){
                float wr = w5tr[q * 5 + r], wi = w5ti[q * 5 + r];
                cr += vr[r] * wr - vi[r] * wi;
                ci += vr[r] * wi + vi[r] * wr;
            }
            int n1 = drevT[5 * u + q];
            int a = k2 * n1;                  // < N = P5*qq + rr
            int qq = a / P5, rr = a - qq * P5;
            float tr = wQr[qq] * wNr[rr] - wQi[qq] * wNi[rr];
            float ti = wQr[qq] * wNi[rr] + wQi[qq] * wNr[rr];
            Br[base + q * Q] = cr * tr - ci * ti;
            Bi[base + q * Q] = cr * ti + ci * tr;
        }
    }
    __syncthreads();
    // ---- wave-local Q-point FFT over k2 (register shuffle, plus sign) ----
    const int w = tid >> 6, lane = tid & 63;
    const int lpos = lane & (GROUPW - 1);
    const int rowoff = lane / GROUPW;
    float fr_[NPASS][E], fi_[NPASS][E];
    #pragma unroll
    for (int i = 0; i < NPASS; ++i){
        int row = (w * NPASS + i) * RPP + rowoff;
        int rc = row < P5 ? row : P5 - 1;
        #pragma unroll
        for (int e = 0; e < E; ++e){
            fr_[i][e] = Br[rc * Q + lpos + e * 64];
            fi_[i][e] = Bi[rc * Q + lpos + e * 64];
        }
    }
    __syncthreads();                          // all rows in registers; Bi free
    #pragma unroll
    for (int i = 0; i < NPASS; ++i){
        int row = (w * NPASS + i) * RPP + rowoff;
        if (E == 2){                          // span-64 butterfly is lane-local
            float ar = fr_[i][0], ai = fi_[i][0];
            float br2 = fr_[i][E - 1], bi2 = fi_[i][E - 1];
            float dr = ar - br2, di = ai - bi2;
            float wr = wQr[lane], wi = wQi[lane];      // jt = lane
            fr_[i][0] = ar + br2; fi_[i][0] = ai + bi2;
            fr_[i][E - 1] = dr * wr - di * wi;
            fi_[i][E - 1] = dr * wi + di * wr;
        }
        #pragma unroll
        for (int sp = GROUPW / 2; sp >= 1; sp >>= 1){
            int m = lpos & (sp - 1);
            int jt = m * ((Q / 2) / sp);
            float wr = wQr[jt], wi = wQi[jt];
            bool hi = (lpos & sp) != 0;
            #pragma unroll
            for (int e = 0; e < E; ++e){
                float pr = __shfl_xor(fr_[i][e], sp, 64);
                float pi = __shfl_xor(fi_[i][e], sp, 64);
                if (hi){
                    float dr = pr - fr_[i][e], di = pi - fi_[i][e];
                    fr_[i][e] = dr * wr - di * wi;
                    fi_[i][e] = dr * wi + di * wr;
                } else {
                    fr_[i][e] += pr; fi_[i][e] += pi;
                }
            }
        }
        if (row < P5){
            #pragma unroll
            for (int e = 0; e < E; ++e){
                int slot = lpos + e * 64;     // final in-place position
                int n2 = (int)(__brev((unsigned)slot) >> (32 - LQ));
                float mag = sqrtf(fr_[i][e] * fr_[i][e] + fi_[i][e] * fi_[i][e]);
                int np = drevT[row] + P5 * n2;
                Bi[np + (np >> 5)] = mag;
            }
        }
    }
    __syncthreads();
    // ---- conv: S1[t] = D * sum_n phi(64t - Dn) Mag[n], 2-way tap split ---
    float acc = 0.0f;
    if (tid < 500){
        int t = tid - 250 * (tid / 250);
        int q = tid / 250;
        int m0 = 64 * t;
        int lo = m0 - DHALF;
        int nlo = (lo >= 0) ? ((lo + D - 1) / D) : -((-lo) / D);
        int nhi = (m0 + DHALF) / D;
        int n = nlo + q;
        if (n <= nhi){
            int np = n % N; if (np < 0) np += N;
            int d = m0 - D * n + DHALF;
            for (; n <= nhi; n += 2){
                acc += hfull[d] * Bi[np + (np >> 5)];
                d -= 2 * D;
                np += 2; if (np >= N) np -= N;
            }
        }
        sred[tid] = acc;
    }
    __syncthreads();
    if (tid < 250)
        Schan[(b * NCH + 1 + fi) * NOUT + tid] = (sred[tid] + sred[tid + 250]) * (float)D;
}

// ---- K2: all 36 channels + S0 in one 2368-block dispatch (512 thr) -------
__global__ __launch_bounds__(512, 4) void k_env_all(const float* __restrict__ x,
                                                    const float2* __restrict__ Xf,
                                                    float* __restrict__ Schan){
    __shared__ float Br[8000];
    __shared__ float Bi[8256];                 // complex plane, then padded Mag
    __shared__ float wPr[125], wPi[125];
    __shared__ float wNr[125], wNi[125];
    __shared__ float wQr[128], wQi[128];
    __shared__ float w5tr[25], w5ti[25];
    __shared__ float hfull[2 * DHALF + 1];
    __shared__ int   drevT[125];
    __shared__ float sred[500];

    const int bi = blockIdx.x;
    const int tid = threadIdx.x;
    if (bi < 448){                         // N=8000, D=2,  fi 0-6
        int fi = bi >> 6, b = bi & 63;
        env_body<125, 6>(Xf + (size_t)b * KMAX, Schan, fi, b, tid, Br, Bi,
                         wPr, wPi, wNr, wNi, wQr, wQi, w5tr, w5ti, hfull, drevT, sred);
    } else if (bi < 640){                  // N=4000, D=4,  fi 7-9
        int t = bi - 448;
        int fi = 7 + (t >> 6), b = t & 63;
        env_body<125, 5>(Xf + (size_t)b * KMAX, Schan, fi, b, tid, Br, Bi,
                         wPr, wPi, wNr, wNi, wQr, wQi, w5tr, w5ti, hfull, drevT, sred);
    } else if (bi < 1088){                 // N=3200, D=5,  fi 10-16
        int t = bi - 640;
        int fi = 10 + (t >> 6), b = t & 63;
        env_body<25, 7>(Xf + (size_t)b * KMAX, Schan, fi, b, tid, Br, Bi,
                        wPr, wPi, wNr, wNi, wQr, wQi, w5tr, w5ti, hfull, drevT, sred);
    } else if (bi < 1408){                 // N=2000, D=8,  fi 17-21
        int t = bi - 1088;
        int fi = 17 + (t >> 6), b = t & 63;
        env_body<125, 4>(Xf + (size_t)b * KMAX, Schan, fi, b, tid, Br, Bi,
                         wPr, wPi, wNr, wNi, wQr, wQi, w5tr, w5ti, hfull, drevT, sred);
    } else if (bi < 2304){                 // N=1600, D=10, fi 22-35
        int t = bi - 1408;
        int fi = 22 + (t >> 6), b = t & 63;
        env_body<25, 6>(Xf + (size_t)b * KMAX, Schan, fi, b, tid, Br, Bi,
                        wPr, wPi, wNr, wNi, wQr, wQi, w5tr, w5ti, hfull, drevT, sred);
    } else {                               // S0 channel, one block per batch
        int b = bi - 2304;
        const float* xb = x + (size_t)b * TLEN;
        for (int j = tid; j <= 2 * DHALF; j += 512){
            double st = 1.0 / (TWO_PI * (0.35 / 64.0));
            double dd = (double)(j - DHALF);
            hfull[j] = (float)((0.35 / 64.0) * sqrt(TWO_PI) * exp(-0.5 * dd * dd / (st * st)));
        }
        __syncthreads();
        float acc = 0.0f;
        if (tid < 500){
            int t = tid - 250 * (tid / 250);
            int q = tid / 250;
            int m0 = 64 * t;
            for (int j = q; j <= 2 * DHALF; j += 2){
                int n = m0 - DHALF + j;
                if (n < 0) n += TLEN; else if (n >= TLEN) n -= TLEN;
                acc += hfull[j] * xb[n];
            }
            sred[tid] = acc;
        }
        __syncthreads();
        if (tid < 250)
            Schan[(b * NCH + 0) * NOUT + tid] = sred[tid] + sred[tid + 250];
    }
}

// ---- K4: channel-group means -> f32 --------------------------------------
__global__ __launch_bounds__(256) void k_reduce(const float* __restrict__ Schan,
                                                float* __restrict__ out){
    int o = blockIdx.x * 256 + threadIdx.x;
    if (o >= NBATCH * 3 * NOUT) return;
    int b = o / (3 * NOUT);
    int rem = o - b * 3 * NOUT;
    int g = rem / NOUT;
    int t = rem - g * NOUT;
    int c0 = (g == 0) ? 0 : (g == 1 ? 12 : 24);
    int c1 = (g == 0) ? 12 : (g == 1 ? 24 : 37);
    float s = 0.0f;
    for (int c = c0; c < c1; ++c) s += Schan[(b * NCH + c) * NOUT + t];
    out[o] = s / (float)(c1 - c0);
}

__global__ void k_fill_f32(float* out, int n, float v){
    int i = blockIdx.x * 256 + threadIdx.x;
    if (i < n) out[i] = v;
}

extern "C" void kernel_launch(void* const* d_in, const int* in_sizes, int n_in,
                              void* d_out, int out_size, void* d_ws, size_t ws_size,
                              hipStream_t stream) {
    const float* x = (const float*)d_in[0];
    float* out = (float*)d_out;
    const size_t xf_bytes = (size_t)NBATCH * KMAX * sizeof(float2);          // 4.10 MB
    const size_t schan_bytes = (size_t)NBATCH * NCH * NOUT * sizeof(float);  // 2.37 MB
    const size_t gtmp_bytes = (size_t)NBATCH * 16000 * sizeof(float2);       // 8.19 MB
    if (ws_size < xf_bytes + schan_bytes + gtmp_bytes){
        k_fill_f32<<<(out_size + 255) / 256, 256, 0, stream>>>(out, out_size, 800.0f);
        return;
    }
    float2* Xf = (float2*)d_ws;
    float* Schan = (float*)((char*)d_ws + xf_bytes);
    float2* Gtmp = (float2*)((char*)d_ws + xf_bytes + schan_bytes);

    k_ffta<<<NBATCH * 4, 256, 0, stream>>>(x, Gtmp);
    k_fftb<<<NBATCH * 5, 256, 0, stream>>>(Gtmp, Xf);
    k_env_all<<<2368, 512, 0, stream>>>(x, Xf, Schan);
    k_reduce<<<(NBATCH * 3 * NOUT + 255) / 256, 256, 0, stream>>>(Schan, out);
}

// Round 19
// 144.105 us; speedup vs baseline: 1.2153x; 1.0526x over previous
//
#include <hip/hip_runtime.h>
#include <hip/hip_bf16.h>

#define TLEN 16000
#define NPSI 36
#define NBATCH 64
#define NOUT 250
#define NCH 37
#define DHALF 176            // Gaussian lowpass half-width (6.05 sigma, sigma_t=29.1)
#define KMAX 8000
#define TWO_PI 6.283185307179586

__device__ __forceinline__ int brev7(int q){ return (int)(__brev((unsigned)q) >> 25); }
__device__ __forceinline__ int drev125(int p){
    return (p % 5) * 25 + ((p / 5) % 5) * 5 + (p / 25);
}

// ---- K1a (split): radix-5 over n1 for 32 n2-rows + W16000 twiddle --------
__global__ __launch_bounds__(256) void k_ffta(const float* __restrict__ x,
                                              float2* __restrict__ Gtmp){
    __shared__ float xr[32 * 126], xi[32 * 126];
    __shared__ float w125r[125], w125i[125];  // e^{-2pi j/125}
    __shared__ float w16r[125],  w16i[125];   // e^{-2pi j/16000}
    __shared__ float w128r[128], w128i[128];  // e^{-2pi j/128}
    const int b = blockIdx.x >> 2, g = blockIdx.x & 3, row0 = 32 * g;
    const int tid = threadIdx.x;

    for (int j = tid; j < 125; j += 256){
        double a = -TWO_PI * (double)j / 125.0;
        w125r[j] = (float)cos(a); w125i[j] = (float)sin(a);
        double a2 = -TWO_PI * (double)j / 16000.0;
        w16r[j] = (float)cos(a2); w16i[j] = (float)sin(a2);
    }
    for (int j = tid; j < 128; j += 256){
        double a = -TWO_PI * (double)j / 128.0;
        w128r[j] = (float)cos(a); w128i[j] = (float)sin(a);
    }
    for (int i = tid; i < 32 * 125; i += 256){
        int n1 = i >> 5, lr = i & 31;
        xr[lr * 126 + n1] = x[b * TLEN + 128 * n1 + row0 + lr];
        xi[lr * 126 + n1] = 0.0f;
    }
    int f = 1;
    for (int s = 25; s >= 1; s /= 5, f *= 5){
        __syncthreads();
        for (int task = tid; task < 25 * 32; task += 256){
            int u = task >> 5, lr = task & 31;
            int blk = u / s, m = u - blk * s;
            int base = lr * 126 + blk * 5 * s + m;
            float vr[5], vi[5];
            #pragma unroll
            for (int r = 0; r < 5; ++r){ vr[r] = xr[base + r * s]; vi[r] = xi[base + r * s]; }
            #pragma unroll
            for (int q = 0; q < 5; ++q){
                float cr = vr[0], ci = vi[0];
                #pragma unroll
                for (int r = 1; r < 5; ++r){
                    int w5 = 25 * ((q * r) % 5);
                    float wr = w125r[w5], wi = w125i[w5];
                    cr += vr[r] * wr - vi[r] * wi;
                    ci += vr[r] * wi + vi[r] * wr;
                }
                int jt = (m * q * f) % 125;
                float tr = w125r[jt], ti = w125i[jt];
                xr[base + q * s] = cr * tr - ci * ti;
                xi[base + q * s] = cr * ti + ci * tr;
            }
        }
    }
    __syncthreads();
    for (int i = tid; i < 125 * 32; i += 256){
        int p = i >> 5, lr = i & 31;
        int n2 = row0 + lr;
        int m = drev125(p);
        int a = m * n2;
        int qq = a / 125, rr = a - qq * 125;
        float tr = w16r[rr] * w128r[qq] - w16i[rr] * w128i[qq];
        float ti = w16r[rr] * w128i[qq] + w16i[rr] * w128r[qq];
        float ar = xr[lr * 126 + p], ai = xi[lr * 126 + p];
        Gtmp[((size_t)b * 125 + p) * 128 + n2] =
            make_float2(ar * tr - ai * ti, ar * ti + ai * tr);
    }
}

// ---- K1b (split): radix-2 over n2 for 25 phys cols; emit k<8000 ----------
__global__ __launch_bounds__(256) void k_fftb(const float2* __restrict__ Gtmp,
                                              float2* __restrict__ Xf){
    __shared__ float gr[128 * 26], gi[128 * 26];
    __shared__ float w128r[128], w128i[128];
    const int b = blockIdx.x / 5, p0 = (blockIdx.x % 5) * 25;
    const int tid = threadIdx.x;
    for (int j = tid; j < 128; j += 256){
        double a = -TWO_PI * (double)j / 128.0;
        w128r[j] = (float)cos(a); w128i[j] = (float)sin(a);
    }
    for (int i = tid; i < 25 * 128; i += 256){
        int ml = i >> 7, n2 = i & 127;
        float2 v = Gtmp[((size_t)b * 125 + p0 + ml) * 128 + n2];
        gr[n2 * 26 + ml] = v.x; gi[n2 * 26 + ml] = v.y;
    }
    for (int span = 64; span >= 1; span >>= 1){
        __syncthreads();
        for (int idx = tid; idx < 1600; idx += 256){
            int u = idx / 25, ml = idx - u * 25;
            int blkq = u / span, mm = u % span;
            int i0 = (blkq * 2 * span + mm) * 26 + ml, i1 = i0 + span * 26;
            float ar = gr[i0], ai = gi[i0], br = gr[i1], bi = gi[i1];
            gr[i0] = ar + br; gi[i0] = ai + bi;
            float dr = ar - br, di = ai - bi;
            int jt = mm * (64 / span);
            gr[i1] = dr * w128r[jt] - di * w128i[jt];
            gi[i1] = dr * w128i[jt] + di * w128r[jt];
        }
    }
    __syncthreads();
    for (int idx = tid; idx < 1600; idx += 256){
        int u = idx / 25, ml = idx - u * 25;
        int ad = (2 * u) * 26 + ml;
        int k = drev125(p0 + ml) + 125 * brev7(2 * u);
        Xf[(size_t)b * KMAX + k] = make_float2(gr[ad], gi[ad]);
    }
}

// ---- env body: round-14 structure, with the FINAL k2-FFT pass fused with
// |z| (twiddle==1 there) -> deletes 2 full-N LDS passes + 1 barrier --------
template<int P5, int LQ>
__device__ __forceinline__ void env_body(const float2* __restrict__ Xfb,
                                         float* __restrict__ Schan,
                                         int fi, int b, int tid,
                                         float* Br, float* Bi,
                                         float* wPr, float* wPi,
                                         float* wNr, float* wNi,
                                         float* wQr, float* wQi,
                                         float* w5tr, float* w5ti,
                                         float* hfull, int* drevT, float* sred){
    constexpr int Q = 1 << LQ;
    constexpr int N = P5 * Q;
    constexpr int D = TLEN / N;
    constexpr int S1 = P5 / 5;
    constexpr int EPT = (LQ & 1) ? 2 : 4;             // elems/task in final pass
    constexpr int NTASK = N / EPT;
    constexpr int NFP = (NTASK + 511) / 512;

    const double xi_d = 0.35 * exp2(-(double)fi / 6.0);
    const double r_d  = exp2(1.0 / 6.0);
    const double sig_d = xi_d * (r_d - 1.0) / (r_d + 1.0);
    const float xi = (float)xi_d;
    const float centerT = (float)(xi_d * (double)TLEN);
    const float sigT = (float)(sig_d * (double)TLEN);
    int klo = (int)floorf(centerT - 5.0f * sigT); if (klo < 1) klo = 1;
    int khi = (int)ceilf(centerT + 5.0f * sigT);  if (khi > KMAX - 1) khi = KMAX - 1;
    const float inv2s2 = (float)(1.0 / (2.0 * sig_d * sig_d));

    for (int j = tid; j < P5; j += 512){
        double a = TWO_PI * (double)j / (double)P5;
        wPr[j] = (float)cos(a); wPi[j] = (float)sin(a);
        double a2 = TWO_PI * (double)j / (double)N;
        wNr[j] = (float)cos(a2); wNi[j] = (float)sin(a2);
        drevT[j] = (P5 == 125) ? drev125(j) : ((j % 5) * 5 + j / 5);
    }
    for (int j = tid; j < Q; j += 512){
        double a = TWO_PI * (double)j / (double)Q;
        wQr[j] = (float)cos(a); wQi[j] = (float)sin(a);
    }
    for (int j = tid; j < 25; j += 512){
        double a = TWO_PI * (double)(((j / 5) * (j % 5)) % 5) / 5.0;   // e^{+2pi(qr%5)/5}
        w5tr[j] = (float)cos(a); w5ti[j] = (float)sin(a);
    }
    for (int j = tid; j <= 2 * DHALF; j += 512){
        double st = 1.0 / (TWO_PI * (0.35 / 64.0));
        double dd = (double)(j - DHALF);
        hfull[j] = (float)((0.35 / 64.0) * sqrt(TWO_PI) * exp(-0.5 * dd * dd / (st * st)));
    }
    __syncthreads();
    // ---- radix-5 stage 1 over j, FUSED with psi-weighted global init -----
    for (int task = tid; task < S1 * Q; task += 512){
        int m = task >> LQ, k2 = task & (Q - 1);
        float vr[5], vi[5];
        #pragma unroll
        for (int r = 0; r < 5; ++r){
            int gk = k2 + ((m + r * S1) << LQ);
            float ur = 0.0f, ui = 0.0f;
            if (gk >= klo && gk <= khi){
                float fr = (float)gk * (1.0f / (float)TLEN);
                float d = fr - xi;
                float p = __expf(-d * d * inv2s2) * (1.0f / (float)TLEN);
                float2 Xv = Xfb[gk];
                ur = Xv.x * p; ui = Xv.y * p;
            }
            vr[r] = ur; vi[r] = ui;
        }
        int base = m * Q + k2;
        #pragma unroll
        for (int q = 0; q < 5; ++q){
            float cr = vr[0], ci = vi[0];
            #pragma unroll
            for (int r = 1; r < 5; ++r){
                float wr = w5tr[q * 5 + r], wi = w5ti[q * 5 + r];
                cr += vr[r] * wr - vi[r] * wi;
                ci += vr[r] * wi + vi[r] * wr;
            }
            int jt = m * q;                   // f = 1
            float tr = wPr[jt], ti = wPi[jt];
            Br[base + q * S1 * Q] = cr * tr - ci * ti;
            Bi[base + q * S1 * Q] = cr * ti + ci * tr;
        }
    }
    // ---- middle radix-5 stage (P5=125 only): s=5, f=5 --------------------
    if (P5 == 125){
        __syncthreads();
        for (int task = tid; task < 25 * Q; task += 512){
            int u = task >> LQ, k2 = task & (Q - 1);
            int blk = u / 5, m = u - blk * 5;
            int base = (blk * 25 + m) * Q + k2;
            float vr[5], vi[5];
            #pragma unroll
            for (int r = 0; r < 5; ++r){ vr[r] = Br[base + r * 5 * Q]; vi[r] = Bi[base + r * 5 * Q]; }
            #pragma unroll
            for (int q = 0; q < 5; ++q){
                float cr = vr[0], ci = vi[0];
                #pragma unroll
                for (int r = 1; r < 5; ++r){
                    float wr = w5tr[q * 5 + r], wi = w5ti[q * 5 + r];
                    cr += vr[r] * wr - vi[r] * wi;
                    ci += vr[r] * wi + vi[r] * wr;
                }
                int jt = m * q * 5;           // < 125
                float tr = wPr[jt], ti = wPi[jt];
                Br[base + q * 5 * Q] = cr * tr - ci * ti;
                Bi[base + q * 5 * Q] = cr * ti + ci * tr;
            }
        }
    }
    // ---- final radix-5 stage fused with W_N^{+k2 n1} output twiddle ------
    __syncthreads();
    for (int task = tid; task < S1 * Q; task += 512){
        int u = task >> LQ, k2 = task & (Q - 1);
        int base = (u * 5) * Q + k2;
        float vr[5], vi[5];
        #pragma unroll
        for (int r = 0; r < 5; ++r){ vr[r] = Br[base + r * Q]; vi[r] = Bi[base + r * Q]; }
        #pragma unroll
        for (int q = 0; q < 5; ++q){
            float cr = vr[0], ci = vi[0];
            #pragma unroll
            for (int r = 1; r < 5; ++r){
                float wr = w5tr[q * 5 + r], wi = w5ti[q * 5 + r];
                cr += vr[r] * wr - vi[r] * wi;
                ci += vr[r] * wi + vi[r] * wr;
            }
            int n1 = drevT[5 * u + q];
            int a = k2 * n1;                  // < N = P5*qq + rr
            int qq = a / P5, rr = a - qq * P5;
            float tr = wQr[qq] * wNr[rr] - wQi[qq] * wNi[rr];
            float ti = wQr[qq] * wNi[rr] + wQi[qq] * wNr[rr];
            Br[base + q * Q] = cr * tr - ci * ti;
            Bi[base + q * Q] = cr * ti + ci * tr;
        }
    }
    // ---- radix-4 passes over k2, EXCEPT the final butterfly level --------
    #pragma unroll
    for (int pass = 0; pass + 1 < LQ / 2 + (LQ & 1); ++pass){
        const int Sp = Q >> (1 + 2 * pass);
        const int half = Sp >> 1;
        __syncthreads();
        for (int task = tid; task < P5 * (Q / 4); task += 512){
            int prow = task / (Q / 4), v = task & (Q / 4 - 1);
            int blkq = v / half, m = v - blkq * half;
            int base = prow * Q + blkq * 2 * Sp + m;
            float Ar = Br[base],           Ai = Bi[base];
            float B2r = Br[base + half],   B2i = Bi[base + half];
            float Cr = Br[base + Sp],      Ci = Bi[base + Sp];
            float D2r = Br[base + Sp + half], D2i = Bi[base + Sp + half];
            int jt1 = m * ((Q / 2) / Sp);
            float w1r = wQr[jt1], w1i = wQi[jt1];
            float w2r = wQr[2 * jt1], w2i = wQi[2 * jt1];
            float A1r = Ar + Cr, A1i = Ai + Ci;
            float t1r = Ar - Cr, t1i = Ai - Ci;
            float C1r = t1r * w1r - t1i * w1i, C1i = t1r * w1i + t1i * w1r;
            float B1r = B2r + D2r, B1i = B2i + D2i;
            float t2r = B2r - D2r, t2i = B2i - D2i;
            float t3r = -t2i, t3i = t2r;
            float D1r = t3r * w1r - t3i * w1i, D1i = t3r * w1i + t3i * w1r;
            Br[base] = A1r + B1r;  Bi[base] = A1i + B1i;
            float u1r = A1r - B1r, u1i = A1i - B1i;
            Br[base + half] = u1r * w2r - u1i * w2i;
            Bi[base + half] = u1r * w2i + u1i * w2r;
            Br[base + Sp] = C1r + D1r;  Bi[base + Sp] = C1i + D1i;
            float u2r = C1r - D1r, u2i = C1i - D1i;
            Br[base + Sp + half] = u2r * w2r - u2i * w2i;
            Bi[base + Sp + half] = u2r * w2i + u2i * w2r;
        }
    }
    // Note: for even LQ the loop above runs LQ/2-1 passes (final radix-4
    // level fused below); for odd LQ it runs all LQ/2 (leftover fused).
    __syncthreads();
    // ---- FINAL butterfly level fused with |z| (twiddles are exactly 1) ---
    float magf[NFP][EPT];
    #pragma unroll
    for (int i = 0; i < NFP; ++i){
        int task = tid + 512 * i;
        if (task < NTASK){
            if (LQ & 1){                      // leftover span-1 radix-2
                int p = task / (Q / 2), u = task - p * (Q / 2);
                int i0 = p * Q + 2 * u;
                float ar = Br[i0], ai = Bi[i0], br2 = Br[i0 + 1], bi2 = Bi[i0 + 1];
                float o0r = ar + br2, o0i = ai + bi2;
                float o1r = ar - br2, o1i = ai - bi2;
                magf[i][0] = sqrtf(o0r * o0r + o0i * o0i);
                magf[i][1] = sqrtf(o1r * o1r + o1i * o1i);
            } else {                          // final radix-4 (Sp=2, half=1, m=0)
                int prow = task / (Q / 4), v = task & (Q / 4 - 1);
                int base = prow * Q + 4 * v;
                float Ar = Br[base],     Ai = Bi[base];
                float B2r = Br[base + 1], B2i = Bi[base + 1];
                float Cr = Br[base + 2],  Ci = Bi[base + 2];
                float D2r = Br[base + 3], D2i = Bi[base + 3];
                float A1r = Ar + Cr, A1i = Ai + Ci;
                float C1r = Ar - Cr, C1i = Ai - Ci;
                float B1r = B2r + D2r, B1i = B2i + D2i;
                float t2r = B2r - D2r, t2i = B2i - D2i;
                float D1r = -t2i, D1i = t2r;          // * i (plus sign)
                float o0r = A1r + B1r, o0i = A1i + B1i;
                float o1r = A1r - B1r, o1i = A1i - B1i;
                float o2r = C1r + D1r, o2i = C1i + D1i;
                float o3r = C1r - D1r, o3i = C1i - D1i;
                magf[i][0] = sqrtf(o0r * o0r + o0i * o0i);
                magf[i][1] = sqrtf(o1r * o1r + o1i * o1i);
                magf[i][2] = sqrtf(o2r * o2r + o2i * o2i);
                magf[i][3] = sqrtf(o3r * o3r + o3i * o3i);
            }
        }
    }
    __syncthreads();                          // all final-level reads done
    // ---- scatter mags to padded-linear Bi: np = drevT[row] + P5*brev(slot)
    #pragma unroll
    for (int i = 0; i < NFP; ++i){
        int task = tid + 512 * i;
        if (task < NTASK){
            int row, s0;
            if (LQ & 1){ row = task / (Q / 2); s0 = 2 * (task - row * (Q / 2)); }
            else       { row = task / (Q / 4); s0 = 4 * (task & (Q / 4 - 1)); }
            #pragma unroll
            for (int e = 0; e < EPT; ++e){
                int slot = s0 + e;
                int n2 = (int)(__brev((unsigned)slot) >> (32 - LQ));
                int np = drevT[row] + P5 * n2;
                Bi[np + (np >> 5)] = magf[i][e];
            }
        }
    }
    __syncthreads();
    // ---- conv: S1[t] = D * sum_n phi(64t - Dn) Mag[n], 2-way tap split ---
    float acc = 0.0f;
    if (tid < 500){
        int t = tid - 250 * (tid / 250);
        int q = tid / 250;
        int m0 = 64 * t;
        int lo = m0 - DHALF;
        int nlo = (lo >= 0) ? ((lo + D - 1) / D) : -((-lo) / D);
        int nhi = (m0 + DHALF) / D;
        int n = nlo + q;
        if (n <= nhi){
            int np = n % N; if (np < 0) np += N;
            int d = m0 - D * n + DHALF;
            for (; n <= nhi; n += 2){
                acc += hfull[d] * Bi[np + (np >> 5)];
                d -= 2 * D;
                np += 2; if (np >= N) np -= N;
            }
        }
        sred[tid] = acc;
    }
    __syncthreads();
    if (tid < 250)
        Schan[(b * NCH + 1 + fi) * NOUT + tid] = (sred[tid] + sred[tid + 250]) * (float)D;
}

// ---- K2: all 36 channels + S0 in one 2368-block dispatch (512 thr) -------
__global__ __launch_bounds__(512, 4) void k_env_all(const float* __restrict__ x,
                                                    const float2* __restrict__ Xf,
                                                    float* __restrict__ Schan){
    __shared__ float Br[8000];
    __shared__ float Bi[8256];                 // complex plane, then padded Mag
    __shared__ float wPr[125], wPi[125];
    __shared__ float wNr[125], wNi[125];
    __shared__ float wQr[128], wQi[128];
    __shared__ float w5tr[25], w5ti[25];
    __shared__ float hfull[2 * DHALF + 1];
    __shared__ int   drevT[125];
    __shared__ float sred[500];

    const int bi = blockIdx.x;
    const int tid = threadIdx.x;
    if (bi < 448){                         // N=8000, D=2,  fi 0-6
        int fi = bi >> 6, b = bi & 63;
        env_body<125, 6>(Xf + (size_t)b * KMAX, Schan, fi, b, tid, Br, Bi,
                         wPr, wPi, wNr, wNi, wQr, wQi, w5tr, w5ti, hfull, drevT, sred);
    } else if (bi < 640){                  // N=4000, D=4,  fi 7-9
        int t = bi - 448;
        int fi = 7 + (t >> 6), b = t & 63;
        env_body<125, 5>(Xf + (size_t)b * KMAX, Schan, fi, b, tid, Br, Bi,
                         wPr, wPi, wNr, wNi, wQr, wQi, w5tr, w5ti, hfull, drevT, sred);
    } else if (bi < 1088){                 // N=3200, D=5,  fi 10-16
        int t = bi - 640;
        int fi = 10 + (t >> 6), b = t & 63;
        env_body<25, 7>(Xf + (size_t)b * KMAX, Schan, fi, b, tid, Br, Bi,
                        wPr, wPi, wNr, wNi, wQr, wQi, w5tr, w5ti, hfull, drevT, sred);
    } else if (bi < 1408){                 // N=2000, D=8,  fi 17-21
        int t = bi - 1088;
        int fi = 17 + (t >> 6), b = t & 63;
        env_body<125, 4>(Xf + (size_t)b * KMAX, Schan, fi, b, tid, Br, Bi,
                         wPr, wPi, wNr, wNi, wQr, wQi, w5tr, w5ti, hfull, drevT, sred);
    } else if (bi < 2304){                 // N=1600, D=10, fi 22-35
        int t = bi - 1408;
        int fi = 22 + (t >> 6), b = t & 63;
        env_body<25, 6>(Xf + (size_t)b * KMAX, Schan, fi, b, tid, Br, Bi,
                        wPr, wPi, wNr, wNi, wQr, wQi, w5tr, w5ti, hfull, drevT, sred);
    } else {                               // S0 channel, one block per batch
        int b = bi - 2304;
        const float* xb = x + (size_t)b * TLEN;
        for (int j = tid; j <= 2 * DHALF; j += 512){
            double st = 1.0 / (TWO_PI * (0.35 / 64.0));
            double dd = (double)(j - DHALF);
            hfull[j] = (float)((0.35 / 64.0) * sqrt(TWO_PI) * exp(-0.5 * dd * dd / (st * st)));
        }
        __syncthreads();
        float acc = 0.0f;
        if (tid < 500){
            int t = tid - 250 * (tid / 250);
            int q = tid / 250;
            int m0 = 64 * t;
            for (int j = q; j <= 2 * DHALF; j += 2){
                int n = m0 - DHALF + j;
                if (n < 0) n += TLEN; else if (n >= TLEN) n -= TLEN;
                acc += hfull[j] * xb[n];
            }
            sred[tid] = acc;
        }
        __syncthreads();
        if (tid < 250)
            Schan[(b * NCH + 0) * NOUT + tid] = sred[tid] + sred[tid + 250];
    }
}

// ---- K4: channel-group means -> f32 --------------------------------------
__global__ __launch_bounds__(256) void k_reduce(const float* __restrict__ Schan,
                                                float* __restrict__ out){
    int o = blockIdx.x * 256 + threadIdx.x;
    if (o >= NBATCH * 3 * NOUT) return;
    int b = o / (3 * NOUT);
    int rem = o - b * 3 * NOUT;
    int g = rem / NOUT;
    int t = rem - g * NOUT;
    int c0 = (g == 0) ? 0 : (g == 1 ? 12 : 24);
    int c1 = (g == 0) ? 12 : (g == 1 ? 24 : 37);
    float s = 0.0f;
    for (int c = c0; c < c1; ++c) s += Schan[(b * NCH + c) * NOUT + t];
    out[o] = s / (float)(c1 - c0);
}

__global__ void k_fill_f32(float* out, int n, float v){
    int i = blockIdx.x * 256 + threadIdx.x;
    if (i < n) out[i] = v;
}

extern "C" void kernel_launch(void* const* d_in, const int* in_sizes, int n_in,
                              void* d_out, int out_size, void* d_ws, size_t ws_size,
                              hipStream_t stream) {
    const float* x = (const float*)d_in[0];
    float* out = (float*)d_out;
    const size_t xf_bytes = (size_t)NBATCH * KMAX * sizeof(float2);          // 4.10 MB
    const size_t schan_bytes = (size_t)NBATCH * NCH * NOUT * sizeof(float);  // 2.37 MB
    const size_t gtmp_bytes = (size_t)NBATCH * 16000 * sizeof(float2);       // 8.19 MB
    if (ws_size < xf_bytes + schan_bytes + gtmp_bytes){
        k_fill_f32<<<(out_size + 255) / 256, 256, 0, stream>>>(out, out_size, 800.0f);
        return;
    }
    float2* Xf = (float2*)d_ws;
    float* Schan = (float*)((char*)d_ws + xf_bytes);
    float2* Gtmp = (float2*)((char*)d_ws + xf_bytes + schan_bytes);

    k_ffta<<<NBATCH * 4, 256, 0, stream>>>(x, Gtmp);
    k_fftb<<<NBATCH * 5, 256, 0, stream>>>(Gtmp, Xf);
    k_env_all<<<2368, 512, 0, stream>>>(x, Xf, Schan);
    k_reduce<<<(NBATCH * 3 * NOUT + 255) / 256, 256, 0, stream>>>(Schan, out);
}

// Round 20
// 143.610 us; speedup vs baseline: 1.2195x; 1.0034x over previous
//
#include <hip/hip_runtime.h>
#include <hip/hip_bf16.h>
#include <hip/hip_fp16.h>

#define TLEN 16000
#define NPSI 36
#define NBATCH 64
#define NOUT 250
#define NCH 37
#define DHALF 176            // Gaussian lowpass half-width (6.05 sigma, sigma_t=29.1)
#define KMAX 8000
#define TWO_PI 6.283185307179586

__device__ __forceinline__ int brev7(int q){ return (int)(__brev((unsigned)q) >> 25); }
__device__ __forceinline__ int drev125(int p){
    return (p % 5) * 25 + ((p / 5) % 5) * 5 + (p / 25);
}
__device__ __forceinline__ float h2f(__half h){ return __half2float(h); }
__device__ __forceinline__ __half f2h(float f){ return __float2half(f); }

// ---- K1a (split): radix-5 over n1 for 32 n2-rows + W16000 twiddle --------
__global__ __launch_bounds__(256) void k_ffta(const float* __restrict__ x,
                                              float2* __restrict__ Gtmp){
    __shared__ float xr[32 * 126], xi[32 * 126];
    __shared__ float w125r[125], w125i[125];  // e^{-2pi j/125}
    __shared__ float w16r[125],  w16i[125];   // e^{-2pi j/16000}
    __shared__ float w128r[128], w128i[128];  // e^{-2pi j/128}
    const int b = blockIdx.x >> 2, g = blockIdx.x & 3, row0 = 32 * g;
    const int tid = threadIdx.x;

    for (int j = tid; j < 125; j += 256){
        double a = -TWO_PI * (double)j / 125.0;
        w125r[j] = (float)cos(a); w125i[j] = (float)sin(a);
        double a2 = -TWO_PI * (double)j / 16000.0;
        w16r[j] = (float)cos(a2); w16i[j] = (float)sin(a2);
    }
    for (int j = tid; j < 128; j += 256){
        double a = -TWO_PI * (double)j / 128.0;
        w128r[j] = (float)cos(a); w128i[j] = (float)sin(a);
    }
    for (int i = tid; i < 32 * 125; i += 256){
        int n1 = i >> 5, lr = i & 31;
        xr[lr * 126 + n1] = x[b * TLEN + 128 * n1 + row0 + lr];
        xi[lr * 126 + n1] = 0.0f;
    }
    int f = 1;
    for (int s = 25; s >= 1; s /= 5, f *= 5){
        __syncthreads();
        for (int task = tid; task < 25 * 32; task += 256){
            int u = task >> 5, lr = task & 31;
            int blk = u / s, m = u - blk * s;
            int base = lr * 126 + blk * 5 * s + m;
            float vr[5], vi[5];
            #pragma unroll
            for (int r = 0; r < 5; ++r){ vr[r] = xr[base + r * s]; vi[r] = xi[base + r * s]; }
            #pragma unroll
            for (int q = 0; q < 5; ++q){
                float cr = vr[0], ci = vi[0];
                #pragma unroll
                for (int r = 1; r < 5; ++r){
                    int w5 = 25 * ((q * r) % 5);
                    float wr = w125r[w5], wi = w125i[w5];
                    cr += vr[r] * wr - vi[r] * wi;
                    ci += vr[r] * wi + vi[r] * wr;
                }
                int jt = (m * q * f) % 125;
                float tr = w125r[jt], ti = w125i[jt];
                xr[base + q * s] = cr * tr - ci * ti;
                xi[base + q * s] = cr * ti + ci * tr;
            }
        }
    }
    __syncthreads();
    for (int i = tid; i < 125 * 32; i += 256){
        int p = i >> 5, lr = i & 31;
        int n2 = row0 + lr;
        int m = drev125(p);
        int a = m * n2;
        int qq = a / 125, rr = a - qq * 125;
        float tr = w16r[rr] * w128r[qq] - w16i[rr] * w128i[qq];
        float ti = w16r[rr] * w128i[qq] + w16i[rr] * w128r[qq];
        float ar = xr[lr * 126 + p], ai = xi[lr * 126 + p];
        Gtmp[((size_t)b * 125 + p) * 128 + n2] =
            make_float2(ar * tr - ai * ti, ar * ti + ai * tr);
    }
}

// ---- K1b (split): radix-2 over n2 for 25 phys cols; emit k<8000 ----------
__global__ __launch_bounds__(256) void k_fftb(const float2* __restrict__ Gtmp,
                                              float2* __restrict__ Xf){
    __shared__ float gr[128 * 26], gi[128 * 26];
    __shared__ float w128r[128], w128i[128];
    const int b = blockIdx.x / 5, p0 = (blockIdx.x % 5) * 25;
    const int tid = threadIdx.x;
    for (int j = tid; j < 128; j += 256){
        double a = -TWO_PI * (double)j / 128.0;
        w128r[j] = (float)cos(a); w128i[j] = (float)sin(a);
    }
    for (int i = tid; i < 25 * 128; i += 256){
        int ml = i >> 7, n2 = i & 127;
        float2 v = Gtmp[((size_t)b * 125 + p0 + ml) * 128 + n2];
        gr[n2 * 26 + ml] = v.x; gi[n2 * 26 + ml] = v.y;
    }
    for (int span = 64; span >= 1; span >>= 1){
        __syncthreads();
        for (int idx = tid; idx < 1600; idx += 256){
            int u = idx / 25, ml = idx - u * 25;
            int blkq = u / span, mm = u % span;
            int i0 = (blkq * 2 * span + mm) * 26 + ml, i1 = i0 + span * 26;
            float ar = gr[i0], ai = gi[i0], br = gr[i1], bi = gi[i1];
            gr[i0] = ar + br; gi[i0] = ai + bi;
            float dr = ar - br, di = ai - bi;
            int jt = mm * (64 / span);
            gr[i1] = dr * w128r[jt] - di * w128i[jt];
            gi[i1] = dr * w128i[jt] + di * w128r[jt];
        }
    }
    __syncthreads();
    for (int idx = tid; idx < 1600; idx += 256){
        int u = idx / 25, ml = idx - u * 25;
        int ad = (2 * u) * 26 + ml;
        int k = drev125(p0 + ml) + 125 * brev7(2 * u);
        Xf[(size_t)b * KMAX + k] = make_float2(gr[ad], gi[ad]);
    }
}

// ---- env body: round-19 structure; Br/Bi stored FP16 (compute f32) -------
// LDS ~39 KB -> 4 blocks/CU (32 waves). Mag pad: np + (np>>4) for halves.
template<int P5, int LQ>
__device__ __forceinline__ void env_body(const float2* __restrict__ Xfb,
                                         float* __restrict__ Schan,
                                         int fi, int b, int tid,
                                         __half* Br, __half* Bi,
                                         float* wPr, float* wPi,
                                         float* wNr, float* wNi,
                                         float* wQr, float* wQi,
                                         float* w5tr, float* w5ti,
                                         float* hfull, int* drevT, float* sred){
    constexpr int Q = 1 << LQ;
    constexpr int N = P5 * Q;
    constexpr int D = TLEN / N;
    constexpr int S1 = P5 / 5;
    constexpr int EPT = (LQ & 1) ? 2 : 4;             // elems/task in final pass
    constexpr int NTASK = N / EPT;
    constexpr int NFP = (NTASK + 511) / 512;

    const double xi_d = 0.35 * exp2(-(double)fi / 6.0);
    const double r_d  = exp2(1.0 / 6.0);
    const double sig_d = xi_d * (r_d - 1.0) / (r_d + 1.0);
    const float xi = (float)xi_d;
    const float centerT = (float)(xi_d * (double)TLEN);
    const float sigT = (float)(sig_d * (double)TLEN);
    int klo = (int)floorf(centerT - 5.0f * sigT); if (klo < 1) klo = 1;
    int khi = (int)ceilf(centerT + 5.0f * sigT);  if (khi > KMAX - 1) khi = KMAX - 1;
    const float inv2s2 = (float)(1.0 / (2.0 * sig_d * sig_d));

    for (int j = tid; j < P5; j += 512){
        double a = TWO_PI * (double)j / (double)P5;
        wPr[j] = (float)cos(a); wPi[j] = (float)sin(a);
        double a2 = TWO_PI * (double)j / (double)N;
        wNr[j] = (float)cos(a2); wNi[j] = (float)sin(a2);
        drevT[j] = (P5 == 125) ? drev125(j) : ((j % 5) * 5 + j / 5);
    }
    for (int j = tid; j < Q; j += 512){
        double a = TWO_PI * (double)j / (double)Q;
        wQr[j] = (float)cos(a); wQi[j] = (float)sin(a);
    }
    for (int j = tid; j < 25; j += 512){
        double a = TWO_PI * (double)(((j / 5) * (j % 5)) % 5) / 5.0;   // e^{+2pi(qr%5)/5}
        w5tr[j] = (float)cos(a); w5ti[j] = (float)sin(a);
    }
    for (int j = tid; j <= 2 * DHALF; j += 512){
        double st = 1.0 / (TWO_PI * (0.35 / 64.0));
        double dd = (double)(j - DHALF);
        hfull[j] = (float)((0.35 / 64.0) * sqrt(TWO_PI) * exp(-0.5 * dd * dd / (st * st)));
    }
    __syncthreads();
    // ---- radix-5 stage 1 over j, FUSED with psi-weighted global init -----
    for (int task = tid; task < S1 * Q; task += 512){
        int m = task >> LQ, k2 = task & (Q - 1);
        float vr[5], vi[5];
        #pragma unroll
        for (int r = 0; r < 5; ++r){
            int gk = k2 + ((m + r * S1) << LQ);
            float ur = 0.0f, ui = 0.0f;
            if (gk >= klo && gk <= khi){
                float fr = (float)gk * (1.0f / (float)TLEN);
                float d = fr - xi;
                float p = __expf(-d * d * inv2s2) * (1.0f / (float)TLEN);
                float2 Xv = Xfb[gk];
                ur = Xv.x * p; ui = Xv.y * p;
            }
            vr[r] = ur; vi[r] = ui;
        }
        int base = m * Q + k2;
        #pragma unroll
        for (int q = 0; q < 5; ++q){
            float cr = vr[0], ci = vi[0];
            #pragma unroll
            for (int r = 1; r < 5; ++r){
                float wr = w5tr[q * 5 + r], wi = w5ti[q * 5 + r];
                cr += vr[r] * wr - vi[r] * wi;
                ci += vr[r] * wi + vi[r] * wr;
            }
            int jt = m * q;                   // f = 1
            float tr = wPr[jt], ti = wPi[jt];
            Br[base + q * S1 * Q] = f2h(cr * tr - ci * ti);
            Bi[base + q * S1 * Q] = f2h(cr * ti + ci * tr);
        }
    }
    // ---- middle radix-5 stage (P5=125 only): s=5, f=5 --------------------
    if (P5 == 125){
        __syncthreads();
        for (int task = tid; task < 25 * Q; task += 512){
            int u = task >> LQ, k2 = task & (Q - 1);
            int blk = u / 5, m = u - blk * 5;
            int base = (blk * 25 + m) * Q + k2;
            float vr[5], vi[5];
            #pragma unroll
            for (int r = 0; r < 5; ++r){ vr[r] = h2f(Br[base + r * 5 * Q]); vi[r] = h2f(Bi[base + r * 5 * Q]); }
            #pragma unroll
            for (int q = 0; q < 5; ++q){
                float cr = vr[0], ci = vi[0];
                #pragma unroll
                for (int r = 1; r < 5; ++r){
                    float wr = w5tr[q * 5 + r], wi = w5ti[q * 5 + r];
                    cr += vr[r] * wr - vi[r] * wi;
                    ci += vr[r] * wi + vi[r] * wr;
                }
                int jt = m * q * 5;           // < 125
                float tr = wPr[jt], ti = wPi[jt];
                Br[base + q * 5 * Q] = f2h(cr * tr - ci * ti);
                Bi[base + q * 5 * Q] = f2h(cr * ti + ci * tr);
            }
        }
    }
    // ---- final radix-5 stage fused with W_N^{+k2 n1} output twiddle ------
    __syncthreads();
    for (int task = tid; task < S1 * Q; task += 512){
        int u = task >> LQ, k2 = task & (Q - 1);
        int base = (u * 5) * Q + k2;
        float vr[5], vi[5];
        #pragma unroll
        for (int r = 0; r < 5; ++r){ vr[r] = h2f(Br[base + r * Q]); vi[r] = h2f(Bi[base + r * Q]); }
        #pragma unroll
        for (int q = 0; q < 5; ++q){
            float cr = vr[0], ci = vi[0];
            #pragma unroll
            for (int r = 1; r < 5; ++r){
                float wr = w5tr[q * 5 + r], wi = w5ti[q * 5 + r];
                cr += vr[r] * wr - vi[r] * wi;
                ci += vr[r] * wi + vi[r] * wr;
            }
            int n1 = drevT[5 * u + q];
            int a = k2 * n1;                  // < N = P5*qq + rr
            int qq = a / P5, rr = a - qq * P5;
            float tr = wQr[qq] * wNr[rr] - wQi[qq] * wNi[rr];
            float ti = wQr[qq] * wNi[rr] + wQi[qq] * wNr[rr];
            Br[base + q * Q] = f2h(cr * tr - ci * ti);
            Bi[base + q * Q] = f2h(cr * ti + ci * tr);
        }
    }
    // ---- radix-4 passes over k2, EXCEPT the final butterfly level --------
    #pragma unroll
    for (int pass = 0; pass + 1 < LQ / 2 + (LQ & 1); ++pass){
        const int Sp = Q >> (1 + 2 * pass);
        const int half = Sp >> 1;
        __syncthreads();
        for (int task = tid; task < P5 * (Q / 4); task += 512){
            int prow = task / (Q / 4), v = task & (Q / 4 - 1);
            int blkq = v / half, m = v - blkq * half;
            int base = prow * Q + blkq * 2 * Sp + m;
            float Ar = h2f(Br[base]),           Ai = h2f(Bi[base]);
            float B2r = h2f(Br[base + half]),   B2i = h2f(Bi[base + half]);
            float Cr = h2f(Br[base + Sp]),      Ci = h2f(Bi[base + Sp]);
            float D2r = h2f(Br[base + Sp + half]), D2i = h2f(Bi[base + Sp + half]);
            int jt1 = m * ((Q / 2) / Sp);
            float w1r = wQr[jt1], w1i = wQi[jt1];
            float w2r = wQr[2 * jt1], w2i = wQi[2 * jt1];
            float A1r = Ar + Cr, A1i = Ai + Ci;
            float t1r = Ar - Cr, t1i = Ai - Ci;
            float C1r = t1r * w1r - t1i * w1i, C1i = t1r * w1i + t1i * w1r;
            float B1r = B2r + D2r, B1i = B2i + D2i;
            float t2r = B2r - D2r, t2i = B2i - D2i;
            float t3r = -t2i, t3i = t2r;
            float D1r = t3r * w1r - t3i * w1i, D1i = t3r * w1i + t3i * w1r;
            Br[base] = f2h(A1r + B1r);  Bi[base] = f2h(A1i + B1i);
            float u1r = A1r - B1r, u1i = A1i - B1i;
            Br[base + half] = f2h(u1r * w2r - u1i * w2i);
            Bi[base + half] = f2h(u1r * w2i + u1i * w2r);
            Br[base + Sp] = f2h(C1r + D1r);  Bi[base + Sp] = f2h(C1i + D1i);
            float u2r = C1r - D1r, u2i = C1i - D1i;
            Br[base + Sp + half] = f2h(u2r * w2r - u2i * w2i);
            Bi[base + Sp + half] = f2h(u2r * w2i + u2i * w2r);
        }
    }
    __syncthreads();
    // ---- FINAL butterfly level fused with |z| (twiddles are exactly 1) ---
    float magf[NFP][EPT];
    #pragma unroll
    for (int i = 0; i < NFP; ++i){
        int task = tid + 512 * i;
        if (task < NTASK){
            if (LQ & 1){                      // leftover span-1 radix-2
                int p = task / (Q / 2), u = task - p * (Q / 2);
                int i0 = p * Q + 2 * u;
                float ar = h2f(Br[i0]), ai = h2f(Bi[i0]);
                float br2 = h2f(Br[i0 + 1]), bi2 = h2f(Bi[i0 + 1]);
                float o0r = ar + br2, o0i = ai + bi2;
                float o1r = ar - br2, o1i = ai - bi2;
                magf[i][0] = sqrtf(o0r * o0r + o0i * o0i);
                magf[i][1] = sqrtf(o1r * o1r + o1i * o1i);
            } else {                          // final radix-4 (Sp=2, half=1, m=0)
                int prow = task / (Q / 4), v = task & (Q / 4 - 1);
                int base = prow * Q + 4 * v;
                float Ar = h2f(Br[base]),     Ai = h2f(Bi[base]);
                float B2r = h2f(Br[base + 1]), B2i = h2f(Bi[base + 1]);
                float Cr = h2f(Br[base + 2]),  Ci = h2f(Bi[base + 2]);
                float D2r = h2f(Br[base + 3]), D2i = h2f(Bi[base + 3]);
                float A1r = Ar + Cr, A1i = Ai + Ci;
                float C1r = Ar - Cr, C1i = Ai - Ci;
                float B1r = B2r + D2r, B1i = B2i + D2i;
                float t2r = B2r - D2r, t2i = B2i - D2i;
                float D1r = -t2i, D1i = t2r;          // * i (plus sign)
                float o0r = A1r + B1r, o0i = A1i + B1i;
                float o1r = A1r - B1r, o1i = A1i - B1i;
                float o2r = C1r + D1r, o2i = C1i + D1i;
                float o3r = C1r - D1r, o3i = C1i - D1i;
                magf[i][0] = sqrtf(o0r * o0r + o0i * o0i);
                magf[i][1] = sqrtf(o1r * o1r + o1i * o1i);
                magf[i][2] = sqrtf(o2r * o2r + o2i * o2i);
                magf[i][3] = sqrtf(o3r * o3r + o3i * o3i);
            }
        }
    }
    __syncthreads();                          // all final-level reads done
    // ---- scatter mags to padded-linear Bi (half): np + (np>>4) -----------
    #pragma unroll
    for (int i = 0; i < NFP; ++i){
        int task = tid + 512 * i;
        if (task < NTASK){
            int row, s0;
            if (LQ & 1){ row = task / (Q / 2); s0 = 2 * (task - row * (Q / 2)); }
            else       { row = task / (Q / 4); s0 = 4 * (task & (Q / 4 - 1)); }
            #pragma unroll
            for (int e = 0; e < EPT; ++e){
                int slot = s0 + e;
                int n2 = (int)(__brev((unsigned)slot) >> (32 - LQ));
                int np = drevT[row] + P5 * n2;
                Bi[np + (np >> 4)] = f2h(magf[i][e]);
            }
        }
    }
    __syncthreads();
    // ---- conv: S1[t] = D * sum_n phi(64t - Dn) Mag[n], 2-way tap split ---
    float acc = 0.0f;
    if (tid < 500){
        int t = tid - 250 * (tid / 250);
        int q = tid / 250;
        int m0 = 64 * t;
        int lo = m0 - DHALF;
        int nlo = (lo >= 0) ? ((lo + D - 1) / D) : -((-lo) / D);
        int nhi = (m0 + DHALF) / D;
        int n = nlo + q;
        if (n <= nhi){
            int np = n % N; if (np < 0) np += N;
            int d = m0 - D * n + DHALF;
            for (; n <= nhi; n += 2){
                acc += hfull[d] * h2f(Bi[np + (np >> 4)]);
                d -= 2 * D;
                np += 2; if (np >= N) np -= N;
            }
        }
        sred[tid] = acc;
    }
    __syncthreads();
    if (tid < 250)
        Schan[(b * NCH + 1 + fi) * NOUT + tid] = (sred[tid] + sred[tid + 250]) * (float)D;
}

// ---- K2: all 36 channels + S0 in one 2368-block dispatch (512 thr) -------
// LDS ~39.2 KB -> 4 blocks/CU x 8 waves = full 32 waves/CU.
__global__ __launch_bounds__(512, 4) void k_env_all(const float* __restrict__ x,
                                                    const float2* __restrict__ Xf,
                                                    float* __restrict__ Schan){
    __shared__ __half Br[8000];
    __shared__ __half Bi[8502];                // complex plane, then padded Mag
    __shared__ float wPr[125], wPi[125];
    __shared__ float wNr[125], wNi[125];
    __shared__ float wQr[128], wQi[128];
    __shared__ float w5tr[25], w5ti[25];
    __shared__ float hfull[2 * DHALF + 1];
    __shared__ int   drevT[125];
    __shared__ float sred[500];

    const int bi = blockIdx.x;
    const int tid = threadIdx.x;
    if (bi < 448){                         // N=8000, D=2,  fi 0-6
        int fi = bi >> 6, b = bi & 63;
        env_body<125, 6>(Xf + (size_t)b * KMAX, Schan, fi, b, tid, Br, Bi,
                         wPr, wPi, wNr, wNi, wQr, wQi, w5tr, w5ti, hfull, drevT, sred);
    } else if (bi < 640){                  // N=4000, D=4,  fi 7-9
        int t = bi - 448;
        int fi = 7 + (t >> 6), b = t & 63;
        env_body<125, 5>(Xf + (size_t)b * KMAX, Schan, fi, b, tid, Br, Bi,
                         wPr, wPi, wNr, wNi, wQr, wQi, w5tr, w5ti, hfull, drevT, sred);
    } else if (bi < 1088){                 // N=3200, D=5,  fi 10-16
        int t = bi - 640;
        int fi = 10 + (t >> 6), b = t & 63;
        env_body<25, 7>(Xf + (size_t)b * KMAX, Schan, fi, b, tid, Br, Bi,
                        wPr, wPi, wNr, wNi, wQr, wQi, w5tr, w5ti, hfull, drevT, sred);
    } else if (bi < 1408){                 // N=2000, D=8,  fi 17-21
        int t = bi - 1088;
        int fi = 17 + (t >> 6), b = t & 63;
        env_body<125, 4>(Xf + (size_t)b * KMAX, Schan, fi, b, tid, Br, Bi,
                         wPr, wPi, wNr, wNi, wQr, wQi, w5tr, w5ti, hfull, drevT, sred);
    } else if (bi < 2304){                 // N=1600, D=10, fi 22-35
        int t = bi - 1408;
        int fi = 22 + (t >> 6), b = t & 63;
        env_body<25, 6>(Xf + (size_t)b * KMAX, Schan, fi, b, tid, Br, Bi,
                        wPr, wPi, wNr, wNi, wQr, wQi, w5tr, w5ti, hfull, drevT, sred);
    } else {                               // S0 channel, one block per batch
        int b = bi - 2304;
        const float* xb = x + (size_t)b * TLEN;
        for (int j = tid; j <= 2 * DHALF; j += 512){
            double st = 1.0 / (TWO_PI * (0.35 / 64.0));
            double dd = (double)(j - DHALF);
            hfull[j] = (float)((0.35 / 64.0) * sqrt(TWO_PI) * exp(-0.5 * dd * dd / (st * st)));
        }
        __syncthreads();
        float acc = 0.0f;
        if (tid < 500){
            int t = tid - 250 * (tid / 250);
            int q = tid / 250;
            int m0 = 64 * t;
            for (int j = q; j <= 2 * DHALF; j += 2){
                int n = m0 - DHALF + j;
                if (n < 0) n += TLEN; else if (n >= TLEN) n -= TLEN;
                acc += hfull[j] * xb[n];
            }
            sred[tid] = acc;
        }
        __syncthreads();
        if (tid < 250)
            Schan[(b * NCH + 0) * NOUT + tid] = sred[tid] + sred[tid + 250];
    }
}

// ---- K4: channel-group means -> f32 --------------------------------------
__global__ __launch_bounds__(256) void k_reduce(const float* __restrict__ Schan,
                                                float* __restrict__ out){
    int o = blockIdx.x * 256 + threadIdx.x;
    if (o >= NBATCH * 3 * NOUT) return;
    int b = o / (3 * NOUT);
    int rem = o - b * 3 * NOUT;
    int g = rem / NOUT;
    int t = rem - g * NOUT;
    int c0 = (g == 0) ? 0 : (g == 1 ? 12 : 24);
    int c1 = (g == 0) ? 12 : (g == 1 ? 24 : 37);
    float s = 0.0f;
    for (int c = c0; c < c1; ++c) s += Schan[(b * NCH + c) * NOUT + t];
    out[o] = s / (float)(c1 - c0);
}

__global__ void k_fill_f32(float* out, int n, float v){
    int i = blockIdx.x * 256 + threadIdx.x;
    if (i < n) out[i] = v;
}

extern "C" void kernel_launch(void* const* d_in, const int* in_sizes, int n_in,
                              void* d_out, int out_size, void* d_ws, size_t ws_size,
                              hipStream_t stream) {
    const float* x = (const float*)d_in[0];
    float* out = (float*)d_out;
    const size_t xf_bytes = (size_t)NBATCH * KMAX * sizeof(float2);          // 4.10 MB
    const size_t schan_bytes = (size_t)NBATCH * NCH * NOUT * sizeof(float);  // 2.37 MB
    const size_t gtmp_bytes = (size_t)NBATCH * 16000 * sizeof(float2);       // 8.19 MB
    if (ws_size < xf_bytes + schan_bytes + gtmp_bytes){
        k_fill_f32<<<(out_size + 255) / 256, 256, 0, stream>>>(out, out_size, 800.0f);
        return;
    }
    float2* Xf = (float2*)d_ws;
    float* Schan = (float*)((char*)d_ws + xf_bytes);
    float2* Gtmp = (float2*)((char*)d_ws + xf_bytes + schan_bytes);

    k_ffta<<<NBATCH * 4, 256, 0, stream>>>(x, Gtmp);
    k_fftb<<<NBATCH * 5, 256, 0, stream>>>(Gtmp, Xf);
    k_env_all<<<2368, 512, 0, stream>>>(x, Xf, Schan);
    k_reduce<<<(NBATCH * 3 * NOUT + 255) / 256, 256, 0, stream>>>(Schan, out);
}

// Round 21
// 135.924 us; speedup vs baseline: 1.2885x; 1.0565x over previous
//
#include <hip/hip_runtime.h>
#include <hip/hip_bf16.h>
#include <hip/hip_fp16.h>

#define TLEN 16000
#define NPSI 36
#define NBATCH 64
#define NOUT 250
#define NCH 37
#define DHALF 176            // Gaussian lowpass half-width (6.05 sigma, sigma_t=29.1)
#define KMAX 8000
#define TWO_PI 6.283185307179586

__device__ __forceinline__ int brev7(int q){ return (int)(__brev((unsigned)q) >> 25); }
__device__ __forceinline__ int drev125(int p){
    return (p % 5) * 25 + ((p / 5) % 5) * 5 + (p / 25);
}
__device__ __forceinline__ float h2f(__half h){ return __half2float(h); }
__device__ __forceinline__ __half f2h(float f){ return __float2half(f); }

// ---- K1a: radix-5 over n1 for 16 n2-rows + W16000 twiddle (512 blocks) ---
__global__ __launch_bounds__(256) void k_ffta(const float* __restrict__ x,
                                              float2* __restrict__ Gtmp){
    __shared__ float xr[16 * 126], xi[16 * 126];
    __shared__ float w125r[125], w125i[125];  // e^{-2pi j/125}
    __shared__ float w16r[125],  w16i[125];   // e^{-2pi j/16000}
    __shared__ float w128r[128], w128i[128];  // e^{-2pi j/128}
    const int b = blockIdx.x >> 3, g = blockIdx.x & 7, row0 = 16 * g;
    const int tid = threadIdx.x;

    for (int j = tid; j < 125; j += 256){
        double a = -TWO_PI * (double)j / 125.0;
        w125r[j] = (float)cos(a); w125i[j] = (float)sin(a);
        double a2 = -TWO_PI * (double)j / 16000.0;
        w16r[j] = (float)cos(a2); w16i[j] = (float)sin(a2);
    }
    for (int j = tid; j < 128; j += 256){
        double a = -TWO_PI * (double)j / 128.0;
        w128r[j] = (float)cos(a); w128i[j] = (float)sin(a);
    }
    for (int i = tid; i < 16 * 125; i += 256){
        int n1 = i >> 4, lr = i & 15;
        xr[lr * 126 + n1] = x[b * TLEN + 128 * n1 + row0 + lr];
        xi[lr * 126 + n1] = 0.0f;
    }
    int f = 1;
    for (int s = 25; s >= 1; s /= 5, f *= 5){
        __syncthreads();
        for (int task = tid; task < 25 * 16; task += 256){
            int u = task >> 4, lr = task & 15;
            int blk = u / s, m = u - blk * s;
            int base = lr * 126 + blk * 5 * s + m;
            float vr[5], vi[5];
            #pragma unroll
            for (int r = 0; r < 5; ++r){ vr[r] = xr[base + r * s]; vi[r] = xi[base + r * s]; }
            #pragma unroll
            for (int q = 0; q < 5; ++q){
                float cr = vr[0], ci = vi[0];
                #pragma unroll
                for (int r = 1; r < 5; ++r){
                    int w5 = 25 * ((q * r) % 5);
                    float wr = w125r[w5], wi = w125i[w5];
                    cr += vr[r] * wr - vi[r] * wi;
                    ci += vr[r] * wi + vi[r] * wr;
                }
                int jt = (m * q * f) % 125;
                float tr = w125r[jt], ti = w125i[jt];
                xr[base + q * s] = cr * tr - ci * ti;
                xi[base + q * s] = cr * ti + ci * tr;
            }
        }
    }
    __syncthreads();
    for (int i = tid; i < 125 * 16; i += 256){
        int p = i >> 4, lr = i & 15;
        int n2 = row0 + lr;
        int m = drev125(p);
        int a = m * n2;
        int qq = a / 125, rr = a - qq * 125;
        float tr = w16r[rr] * w128r[qq] - w16i[rr] * w128i[qq];
        float ti = w16r[rr] * w128i[qq] + w16i[rr] * w128r[qq];
        float ar = xr[lr * 126 + p], ai = xi[lr * 126 + p];
        Gtmp[((size_t)b * 125 + p) * 128 + n2] =
            make_float2(ar * tr - ai * ti, ar * ti + ai * tr);
    }
}

// ---- K1b: radix-2 over n2 for 5 phys cols (1600 blocks, 128 thr) ---------
__global__ __launch_bounds__(128) void k_fftb(const float2* __restrict__ Gtmp,
                                              float2* __restrict__ Xf){
    __shared__ float gr[128 * 5], gi[128 * 5];
    __shared__ float w128r[128], w128i[128];
    const int b = blockIdx.x / 25, p0 = (blockIdx.x % 25) * 5;
    const int tid = threadIdx.x;
    for (int j = tid; j < 128; j += 128){
        double a = -TWO_PI * (double)j / 128.0;
        w128r[j] = (float)cos(a); w128i[j] = (float)sin(a);
    }
    for (int i = tid; i < 5 * 128; i += 128){
        int ml = i >> 7, n2 = i & 127;
        float2 v = Gtmp[((size_t)b * 125 + p0 + ml) * 128 + n2];
        gr[n2 * 5 + ml] = v.x; gi[n2 * 5 + ml] = v.y;
    }
    for (int span = 64; span >= 1; span >>= 1){
        __syncthreads();
        for (int idx = tid; idx < 320; idx += 128){
            int u = idx / 5, ml = idx - u * 5;
            int blkq = u / span, mm = u % span;
            int i0 = (blkq * 2 * span + mm) * 5 + ml, i1 = i0 + span * 5;
            float ar = gr[i0], ai = gi[i0], br = gr[i1], bi = gi[i1];
            gr[i0] = ar + br; gi[i0] = ai + bi;
            float dr = ar - br, di = ai - bi;
            int jt = mm * (64 / span);
            gr[i1] = dr * w128r[jt] - di * w128i[jt];
            gi[i1] = dr * w128i[jt] + di * w128r[jt];
        }
    }
    __syncthreads();
    for (int idx = tid; idx < 320; idx += 128){
        int u = idx / 5, ml = idx - u * 5;
        int ad = (2 * u) * 5 + ml;
        int k = drev125(p0 + ml) + 125 * brev7(2 * u);
        Xf[(size_t)b * KMAX + k] = make_float2(gr[ad], gi[ad]);
    }
}

// ---- env body: round-20 verbatim (fp16 LDS, f32 compute) -----------------
template<int P5, int LQ>
__device__ __forceinline__ void env_body(const float2* __restrict__ Xfb,
                                         float* __restrict__ Schan,
                                         int fi, int b, int tid,
                                         __half* Br, __half* Bi,
                                         float* wPr, float* wPi,
                                         float* wNr, float* wNi,
                                         float* wQr, float* wQi,
                                         float* w5tr, float* w5ti,
                                         float* hfull, int* drevT, float* sred){
    constexpr int Q = 1 << LQ;
    constexpr int N = P5 * Q;
    constexpr int D = TLEN / N;
    constexpr int S1 = P5 / 5;
    constexpr int EPT = (LQ & 1) ? 2 : 4;             // elems/task in final pass
    constexpr int NTASK = N / EPT;
    constexpr int NFP = (NTASK + 511) / 512;

    const double xi_d = 0.35 * exp2(-(double)fi / 6.0);
    const double r_d  = exp2(1.0 / 6.0);
    const double sig_d = xi_d * (r_d - 1.0) / (r_d + 1.0);
    const float xi = (float)xi_d;
    const float centerT = (float)(xi_d * (double)TLEN);
    const float sigT = (float)(sig_d * (double)TLEN);
    int klo = (int)floorf(centerT - 5.0f * sigT); if (klo < 1) klo = 1;
    int khi = (int)ceilf(centerT + 5.0f * sigT);  if (khi > KMAX - 1) khi = KMAX - 1;
    const float inv2s2 = (float)(1.0 / (2.0 * sig_d * sig_d));

    for (int j = tid; j < P5; j += 512){
        double a = TWO_PI * (double)j / (double)P5;
        wPr[j] = (float)cos(a); wPi[j] = (float)sin(a);
        double a2 = TWO_PI * (double)j / (double)N;
        wNr[j] = (float)cos(a2); wNi[j] = (float)sin(a2);
        drevT[j] = (P5 == 125) ? drev125(j) : ((j % 5) * 5 + j / 5);
    }
    for (int j = tid; j < Q; j += 512){
        double a = TWO_PI * (double)j / (double)Q;
        wQr[j] = (float)cos(a); wQi[j] = (float)sin(a);
    }
    for (int j = tid; j < 25; j += 512){
        double a = TWO_PI * (double)(((j / 5) * (j % 5)) % 5) / 5.0;   // e^{+2pi(qr%5)/5}
        w5tr[j] = (float)cos(a); w5ti[j] = (float)sin(a);
    }
    for (int j = tid; j <= 2 * DHALF; j += 512){
        double st = 1.0 / (TWO_PI * (0.35 / 64.0));
        double dd = (double)(j - DHALF);
        hfull[j] = (float)((0.35 / 64.0) * sqrt(TWO_PI) * exp(-0.5 * dd * dd / (st * st)));
    }
    __syncthreads();
    // ---- radix-5 stage 1 over j, FUSED with psi-weighted global init -----
    for (int task = tid; task < S1 * Q; task += 512){
        int m = task >> LQ, k2 = task & (Q - 1);
        float vr[5], vi[5];
        #pragma unroll
        for (int r = 0; r < 5; ++r){
            int gk = k2 + ((m + r * S1) << LQ);
            float ur = 0.0f, ui = 0.0f;
            if (gk >= klo && gk <= khi){
                float fr = (float)gk * (1.0f / (float)TLEN);
                float d = fr - xi;
                float p = __expf(-d * d * inv2s2) * (1.0f / (float)TLEN);
                float2 Xv = Xfb[gk];
                ur = Xv.x * p; ui = Xv.y * p;
            }
            vr[r] = ur; vi[r] = ui;
        }
        int base = m * Q + k2;
        #pragma unroll
        for (int q = 0; q < 5; ++q){
            float cr = vr[0], ci = vi[0];
            #pragma unroll
            for (int r = 1; r < 5; ++r){
                float wr = w5tr[q * 5 + r], wi = w5ti[q * 5 + r];
                cr += vr[r] * wr - vi[r] * wi;
                ci += vr[r] * wi + vi[r] * wr;
            }
            int jt = m * q;                   // f = 1
            float tr = wPr[jt], ti = wPi[jt];
            Br[base + q * S1 * Q] = f2h(cr * tr - ci * ti);
            Bi[base + q * S1 * Q] = f2h(cr * ti + ci * tr);
        }
    }
    // ---- middle radix-5 stage (P5=125 only): s=5, f=5 --------------------
    if (P5 == 125){
        __syncthreads();
        for (int task = tid; task < 25 * Q; task += 512){
            int u = task >> LQ, k2 = task & (Q - 1);
            int blk = u / 5, m = u - blk * 5;
            int base = (blk * 25 + m) * Q + k2;
            float vr[5], vi[5];
            #pragma unroll
            for (int r = 0; r < 5; ++r){ vr[r] = h2f(Br[base + r * 5 * Q]); vi[r] = h2f(Bi[base + r * 5 * Q]); }
            #pragma unroll
            for (int q = 0; q < 5; ++q){
                float cr = vr[0], ci = vi[0];
                #pragma unroll
                for (int r = 1; r < 5; ++r){
                    float wr = w5tr[q * 5 + r], wi = w5ti[q * 5 + r];
                    cr += vr[r] * wr - vi[r] * wi;
                    ci += vr[r] * wi + vi[r] * wr;
                }
                int jt = m * q * 5;           // < 125
                float tr = wPr[jt], ti = wPi[jt];
                Br[base + q * 5 * Q] = f2h(cr * tr - ci * ti);
                Bi[base + q * 5 * Q] = f2h(cr * ti + ci * tr);
            }
        }
    }
    // ---- final radix-5 stage fused with W_N^{+k2 n1} output twiddle ------
    __syncthreads();
    for (int task = tid; task < S1 * Q; task += 512){
        int u = task >> LQ, k2 = task & (Q - 1);
        int base = (u * 5) * Q + k2;
        float vr[5], vi[5];
        #pragma unroll
        for (int r = 0; r < 5; ++r){ vr[r] = h2f(Br[base + r * Q]); vi[r] = h2f(Bi[base + r * Q]); }
        #pragma unroll
        for (int q = 0; q < 5; ++q){
            float cr = vr[0], ci = vi[0];
            #pragma unroll
            for (int r = 1; r < 5; ++r){
                float wr = w5tr[q * 5 + r], wi = w5ti[q * 5 + r];
                cr += vr[r] * wr - vi[r] * wi;
                ci += vr[r] * wi + vi[r] * wr;
            }
            int n1 = drevT[5 * u + q];
            int a = k2 * n1;                  // < N = P5*qq + rr
            int qq = a / P5, rr = a - qq * P5;
            float tr = wQr[qq] * wNr[rr] - wQi[qq] * wNi[rr];
            float ti = wQr[qq] * wNi[rr] + wQi[qq] * wNr[rr];
            Br[base + q * Q] = f2h(cr * tr - ci * ti);
            Bi[base + q * Q] = f2h(cr * ti + ci * tr);
        }
    }
    // ---- radix-4 passes over k2, EXCEPT the final butterfly level --------
    #pragma unroll
    for (int pass = 0; pass + 1 < LQ / 2 + (LQ & 1); ++pass){
        const int Sp = Q >> (1 + 2 * pass);
        const int half = Sp >> 1;
        __syncthreads();
        for (int task = tid; task < P5 * (Q / 4); task += 512){
            int prow = task / (Q / 4), v = task & (Q / 4 - 1);
            int blkq = v / half, m = v - blkq * half;
            int base = prow * Q + blkq * 2 * Sp + m;
            float Ar = h2f(Br[base]),           Ai = h2f(Bi[base]);
            float B2r = h2f(Br[base + half]),   B2i = h2f(Bi[base + half]);
            float Cr = h2f(Br[base + Sp]),      Ci = h2f(Bi[base + Sp]);
            float D2r = h2f(Br[base + Sp + half]), D2i = h2f(Bi[base + Sp + half]);
            int jt1 = m * ((Q / 2) / Sp);
            float w1r = wQr[jt1], w1i = wQi[jt1];
            float w2r = wQr[2 * jt1], w2i = wQi[2 * jt1];
            float A1r = Ar + Cr, A1i = Ai + Ci;
            float t1r = Ar - Cr, t1i = Ai - Ci;
            float C1r = t1r * w1r - t1i * w1i, C1i = t1r * w1i + t1i * w1r;
            float B1r = B2r + D2r, B1i = B2i + D2i;
            float t2r = B2r - D2r, t2i = B2i - D2i;
            float t3r = -t2i, t3i = t2r;
            float D1r = t3r * w1r - t3i * w1i, D1i = t3r * w1i + t3i * w1r;
            Br[base] = f2h(A1r + B1r);  Bi[base] = f2h(A1i + B1i);
            float u1r = A1r - B1r, u1i = A1i - B1i;
            Br[base + half] = f2h(u1r * w2r - u1i * w2i);
            Bi[base + half] = f2h(u1r * w2i + u1i * w2r);
            Br[base + Sp] = f2h(C1r + D1r);  Bi[base + Sp] = f2h(C1i + D1i);
            float u2r = C1r - D1r, u2i = C1i - D1i;
            Br[base + Sp + half] = f2h(u2r * w2r - u2i * w2i);
            Bi[base + Sp + half] = f2h(u2r * w2i + u2i * w2r);
        }
    }
    __syncthreads();
    // ---- FINAL butterfly level fused with |z| (twiddles are exactly 1) ---
    float magf[NFP][EPT];
    #pragma unroll
    for (int i = 0; i < NFP; ++i){
        int task = tid + 512 * i;
        if (task < NTASK){
            if (LQ & 1){                      // leftover span-1 radix-2
                int p = task / (Q / 2), u = task - p * (Q / 2);
                int i0 = p * Q + 2 * u;
                float ar = h2f(Br[i0]), ai = h2f(Bi[i0]);
                float br2 = h2f(Br[i0 + 1]), bi2 = h2f(Bi[i0 + 1]);
                float o0r = ar + br2, o0i = ai + bi2;
                float o1r = ar - br2, o1i = ai - bi2;
                magf[i][0] = sqrtf(o0r * o0r + o0i * o0i);
                magf[i][1] = sqrtf(o1r * o1r + o1i * o1i);
            } else {                          // final radix-4 (Sp=2, half=1, m=0)
                int prow = task / (Q / 4), v = task & (Q / 4 - 1);
                int base = prow * Q + 4 * v;
                float Ar = h2f(Br[base]),     Ai = h2f(Bi[base]);
                float B2r = h2f(Br[base + 1]), B2i = h2f(Bi[base + 1]);
                float Cr = h2f(Br[base + 2]),  Ci = h2f(Bi[base + 2]);
                float D2r = h2f(Br[base + 3]), D2i = h2f(Bi[base + 3]);
                float A1r = Ar + Cr, A1i = Ai + Ci;
                float C1r = Ar - Cr, C1i = Ai - Ci;
                float B1r = B2r + D2r, B1i = B2i + D2i;
                float t2r = B2r - D2r, t2i = B2i - D2i;
                float D1r = -t2i, D1i = t2r;          // * i (plus sign)
                float o0r = A1r + B1r, o0i = A1i + B1i;
                float o1r = A1r - B1r, o1i = A1i - B1i;
                float o2r = C1r + D1r, o2i = C1i + D1i;
                float o3r = C1r - D1r, o3i = C1i - D1i;
                magf[i][0] = sqrtf(o0r * o0r + o0i * o0i);
                magf[i][1] = sqrtf(o1r * o1r + o1i * o1i);
                magf[i][2] = sqrtf(o2r * o2r + o2i * o2i);
                magf[i][3] = sqrtf(o3r * o3r + o3i * o3i);
            }
        }
    }
    __syncthreads();                          // all final-level reads done
    // ---- scatter mags to padded-linear Bi (half): np + (np>>4) -----------
    #pragma unroll
    for (int i = 0; i < NFP; ++i){
        int task = tid + 512 * i;
        if (task < NTASK){
            int row, s0;
            if (LQ & 1){ row = task / (Q / 2); s0 = 2 * (task - row * (Q / 2)); }
            else       { row = task / (Q / 4); s0 = 4 * (task & (Q / 4 - 1)); }
            #pragma unroll
            for (int e = 0; e < EPT; ++e){
                int slot = s0 + e;
                int n2 = (int)(__brev((unsigned)slot) >> (32 - LQ));
                int np = drevT[row] + P5 * n2;
                Bi[np + (np >> 4)] = f2h(magf[i][e]);
            }
        }
    }
    __syncthreads();
    // ---- conv: S1[t] = D * sum_n phi(64t - Dn) Mag[n], 2-way tap split ---
    float acc = 0.0f;
    if (tid < 500){
        int t = tid - 250 * (tid / 250);
        int q = tid / 250;
        int m0 = 64 * t;
        int lo = m0 - DHALF;
        int nlo = (lo >= 0) ? ((lo + D - 1) / D) : -((-lo) / D);
        int nhi = (m0 + DHALF) / D;
        int n = nlo + q;
        if (n <= nhi){
            int np = n % N; if (np < 0) np += N;
            int d = m0 - D * n + DHALF;
            for (; n <= nhi; n += 2){
                acc += hfull[d] * h2f(Bi[np + (np >> 4)]);
                d -= 2 * D;
                np += 2; if (np >= N) np -= N;
            }
        }
        sred[tid] = acc;
    }
    __syncthreads();
    if (tid < 250)
        Schan[(b * NCH + 1 + fi) * NOUT + tid] = (sred[tid] + sred[tid + 250]) * (float)D;
}

// ---- K2: all 36 channels + S0 in one 2368-block dispatch (512 thr) -------
__global__ __launch_bounds__(512, 4) void k_env_all(const float* __restrict__ x,
                                                    const float2* __restrict__ Xf,
                                                    float* __restrict__ Schan){
    __shared__ __half Br[8000];
    __shared__ __half Bi[8502];                // complex plane, then padded Mag
    __shared__ float wPr[125], wPi[125];
    __shared__ float wNr[125], wNi[125];
    __shared__ float wQr[128], wQi[128];
    __shared__ float w5tr[25], w5ti[25];
    __shared__ float hfull[2 * DHALF + 1];
    __shared__ int   drevT[125];
    __shared__ float sred[500];

    const int bi = blockIdx.x;
    const int tid = threadIdx.x;
    if (bi < 448){                         // N=8000, D=2,  fi 0-6
        int fi = bi >> 6, b = bi & 63;
        env_body<125, 6>(Xf + (size_t)b * KMAX, Schan, fi, b, tid, Br, Bi,
                         wPr, wPi, wNr, wNi, wQr, wQi, w5tr, w5ti, hfull, drevT, sred);
    } else if (bi < 640){                  // N=4000, D=4,  fi 7-9
        int t = bi - 448;
        int fi = 7 + (t >> 6), b = t & 63;
        env_body<125, 5>(Xf + (size_t)b * KMAX, Schan, fi, b, tid, Br, Bi,
                         wPr, wPi, wNr, wNi, wQr, wQi, w5tr, w5ti, hfull, drevT, sred);
    } else if (bi < 1088){                 // N=3200, D=5,  fi 10-16
        int t = bi - 640;
        int fi = 10 + (t >> 6), b = t & 63;
        env_body<25, 7>(Xf + (size_t)b * KMAX, Schan, fi, b, tid, Br, Bi,
                        wPr, wPi, wNr, wNi, wQr, wQi, w5tr, w5ti, hfull, drevT, sred);
    } else if (bi < 1408){                 // N=2000, D=8,  fi 17-21
        int t = bi - 1088;
        int fi = 17 + (t >> 6), b = t & 63;
        env_body<125, 4>(Xf + (size_t)b * KMAX, Schan, fi, b, tid, Br, Bi,
                         wPr, wPi, wNr, wNi, wQr, wQi, w5tr, w5ti, hfull, drevT, sred);
    } else if (bi < 2304){                 // N=1600, D=10, fi 22-35
        int t = bi - 1408;
        int fi = 22 + (t >> 6), b = t & 63;
        env_body<25, 6>(Xf + (size_t)b * KMAX, Schan, fi, b, tid, Br, Bi,
                        wPr, wPi, wNr, wNi, wQr, wQi, w5tr, w5ti, hfull, drevT, sred);
    } else {                               // S0 channel, one block per batch
        int b = bi - 2304;
        const float* xb = x + (size_t)b * TLEN;
        for (int j = tid; j <= 2 * DHALF; j += 512){
            double st = 1.0 / (TWO_PI * (0.35 / 64.0));
            double dd = (double)(j - DHALF);
            hfull[j] = (float)((0.35 / 64.0) * sqrt(TWO_PI) * exp(-0.5 * dd * dd / (st * st)));
        }
        __syncthreads();
        float acc = 0.0f;
        if (tid < 500){
            int t = tid - 250 * (tid / 250);
            int q = tid / 250;
            int m0 = 64 * t;
            for (int j = q; j <= 2 * DHALF; j += 2){
                int n = m0 - DHALF + j;
                if (n < 0) n += TLEN; else if (n >= TLEN) n -= TLEN;
                acc += hfull[j] * xb[n];
            }
            sred[tid] = acc;
        }
        __syncthreads();
        if (tid < 250)
            Schan[(b * NCH + 0) * NOUT + tid] = sred[tid] + sred[tid + 250];
    }
}

// ---- K4: channel-group means -> f32 --------------------------------------
__global__ __launch_bounds__(256) void k_reduce(const float* __restrict__ Schan,
                                                float* __restrict__ out){
    int o = blockIdx.x * 256 + threadIdx.x;
    if (o >= NBATCH * 3 * NOUT) return;
    int b = o / (3 * NOUT);
    int rem = o - b * 3 * NOUT;
    int g = rem / NOUT;
    int t = rem - g * NOUT;
    int c0 = (g == 0) ? 0 : (g == 1 ? 12 : 24);
    int c1 = (g == 0) ? 12 : (g == 1 ? 24 : 37);
    float s = 0.0f;
    for (int c = c0; c < c1; ++c) s += Schan[(b * NCH + c) * NOUT + t];
    out[o] = s / (float)(c1 - c0);
}

__global__ void k_fill_f32(float* out, int n, float v){
    int i = blockIdx.x * 256 + threadIdx.x;
    if (i < n) out[i] = v;
}

extern "C" void kernel_launch(void* const* d_in, const int* in_sizes, int n_in,
                              void* d_out, int out_size, void* d_ws, size_t ws_size,
                              hipStream_t stream) {
    const float* x = (const float*)d_in[0];
    float* out = (float*)d_out;
    const size_t xf_bytes = (size_t)NBATCH * KMAX * sizeof(float2);          // 4.10 MB
    const size_t schan_bytes = (size_t)NBATCH * NCH * NOUT * sizeof(float);  // 2.37 MB
    const size_t gtmp_bytes = (size_t)NBATCH * 16000 * sizeof(float2);       // 8.19 MB
    if (ws_size < xf_bytes + schan_bytes + gtmp_bytes){
        k_fill_f32<<<(out_size + 255) / 256, 256, 0, stream>>>(out, out_size, 800.0f);
        return;
    }
    float2* Xf = (float2*)d_ws;
    float* Schan = (float*)((char*)d_ws + xf_bytes);
    float2* Gtmp = (float2*)((char*)d_ws + xf_bytes + schan_bytes);

    k_ffta<<<NBATCH * 8, 256, 0, stream>>>(x, Gtmp);
    k_fftb<<<NBATCH * 25, 128, 0, stream>>>(Gtmp, Xf);
    k_env_all<<<2368, 512, 0, stream>>>(x, Xf, Schan);
    k_reduce<<<(NBATCH * 3 * NOUT + 255) / 256, 256, 0, stream>>>(Schan, out);
}

// Round 22
// 135.130 us; speedup vs baseline: 1.2960x; 1.0059x over previous
//
#include <hip/hip_runtime.h>
#include <hip/hip_bf16.h>
#include <hip/hip_fp16.h>

#define TLEN 16000
#define NPSI 36
#define NBATCH 64
#define NOUT 250
#define NCH 37
#define DHALF 176            // Gaussian lowpass half-width (6.05 sigma, sigma_t=29.1)
#define KMAX 8000
#define TWO_PI 6.283185307179586

__device__ __forceinline__ int brev7(int q){ return (int)(__brev((unsigned)q) >> 25); }
__device__ __forceinline__ int drev125(int p){
    return (p % 5) * 25 + ((p / 5) % 5) * 5 + (p / 25);
}
__device__ __forceinline__ float lo2f(__half2 v){ return __low2float(v); }
__device__ __forceinline__ float hi2f(__half2 v){ return __high2float(v); }
__device__ __forceinline__ __half2 pk2(float r, float i){
    return __halves2half2(__float2half(r), __float2half(i));
}

// ---- K1a: radix-5 over n1 for 16 n2-rows + W16000 twiddle (512 blocks) ---
__global__ __launch_bounds__(256) void k_ffta(const float* __restrict__ x,
                                              float2* __restrict__ Gtmp){
    __shared__ float xr[16 * 126], xi[16 * 126];
    __shared__ float w125r[125], w125i[125];  // e^{-2pi j/125}
    __shared__ float w16r[125],  w16i[125];   // e^{-2pi j/16000}
    __shared__ float w128r[128], w128i[128];  // e^{-2pi j/128}
    const int b = blockIdx.x >> 3, g = blockIdx.x & 7, row0 = 16 * g;
    const int tid = threadIdx.x;

    for (int j = tid; j < 125; j += 256){
        double a = -TWO_PI * (double)j / 125.0;
        w125r[j] = (float)cos(a); w125i[j] = (float)sin(a);
        double a2 = -TWO_PI * (double)j / 16000.0;
        w16r[j] = (float)cos(a2); w16i[j] = (float)sin(a2);
    }
    for (int j = tid; j < 128; j += 256){
        double a = -TWO_PI * (double)j / 128.0;
        w128r[j] = (float)cos(a); w128i[j] = (float)sin(a);
    }
    for (int i = tid; i < 16 * 125; i += 256){
        int n1 = i >> 4, lr = i & 15;
        xr[lr * 126 + n1] = x[b * TLEN + 128 * n1 + row0 + lr];
        xi[lr * 126 + n1] = 0.0f;
    }
    int f = 1;
    for (int s = 25; s >= 1; s /= 5, f *= 5){
        __syncthreads();
        for (int task = tid; task < 25 * 16; task += 256){
            int u = task >> 4, lr = task & 15;
            int blk = u / s, m = u - blk * s;
            int base = lr * 126 + blk * 5 * s + m;
            float vr[5], vi[5];
            #pragma unroll
            for (int r = 0; r < 5; ++r){ vr[r] = xr[base + r * s]; vi[r] = xi[base + r * s]; }
            #pragma unroll
            for (int q = 0; q < 5; ++q){
                float cr = vr[0], ci = vi[0];
                #pragma unroll
                for (int r = 1; r < 5; ++r){
                    int w5 = 25 * ((q * r) % 5);
                    float wr = w125r[w5], wi = w125i[w5];
                    cr += vr[r] * wr - vi[r] * wi;
                    ci += vr[r] * wi + vi[r] * wr;
                }
                int jt = (m * q * f) % 125;
                float tr = w125r[jt], ti = w125i[jt];
                xr[base + q * s] = cr * tr - ci * ti;
                xi[base + q * s] = cr * ti + ci * tr;
            }
        }
    }
    __syncthreads();
    for (int i = tid; i < 125 * 16; i += 256){
        int p = i >> 4, lr = i & 15;
        int n2 = row0 + lr;
        int m = drev125(p);
        int a = m * n2;
        int qq = a / 125, rr = a - qq * 125;
        float tr = w16r[rr] * w128r[qq] - w16i[rr] * w128i[qq];
        float ti = w16r[rr] * w128i[qq] + w16i[rr] * w128r[qq];
        float ar = xr[lr * 126 + p], ai = xi[lr * 126 + p];
        Gtmp[((size_t)b * 125 + p) * 128 + n2] =
            make_float2(ar * tr - ai * ti, ar * ti + ai * tr);
    }
}

// ---- K1b: radix-2 over n2 for 5 phys cols (1600 blocks, 128 thr) ---------
__global__ __launch_bounds__(128) void k_fftb(const float2* __restrict__ Gtmp,
                                              float2* __restrict__ Xf){
    __shared__ float gr[128 * 5], gi[128 * 5];
    __shared__ float w128r[128], w128i[128];
    const int b = blockIdx.x / 25, p0 = (blockIdx.x % 25) * 5;
    const int tid = threadIdx.x;
    for (int j = tid; j < 128; j += 128){
        double a = -TWO_PI * (double)j / 128.0;
        w128r[j] = (float)cos(a); w128i[j] = (float)sin(a);
    }
    for (int i = tid; i < 5 * 128; i += 128){
        int ml = i >> 7, n2 = i & 127;
        float2 v = Gtmp[((size_t)b * 125 + p0 + ml) * 128 + n2];
        gr[n2 * 5 + ml] = v.x; gi[n2 * 5 + ml] = v.y;
    }
    for (int span = 64; span >= 1; span >>= 1){
        __syncthreads();
        for (int idx = tid; idx < 320; idx += 128){
            int u = idx / 5, ml = idx - u * 5;
            int blkq = u / span, mm = u % span;
            int i0 = (blkq * 2 * span + mm) * 5 + ml, i1 = i0 + span * 5;
            float ar = gr[i0], ai = gi[i0], br = gr[i1], bi = gi[i1];
            gr[i0] = ar + br; gi[i0] = ai + bi;
            float dr = ar - br, di = ai - bi;
            int jt = mm * (64 / span);
            gr[i1] = dr * w128r[jt] - di * w128i[jt];
            gi[i1] = dr * w128i[jt] + di * w128r[jt];
        }
    }
    __syncthreads();
    for (int idx = tid; idx < 320; idx += 128){
        int u = idx / 5, ml = idx - u * 5;
        int ad = (2 * u) * 5 + ml;
        int k = drev125(p0 + ml) + 125 * brev7(2 * u);
        Xf[(size_t)b * KMAX + k] = make_float2(gr[ad], gi[ad]);
    }
}

// ---- env body: round-21 structure; complex stored INTERLEAVED __half2 ----
// One 4-byte LDS op per complex access (half the op count of split-half).
template<int P5, int LQ>
__device__ __forceinline__ void env_body(const float2* __restrict__ Xfb,
                                         float* __restrict__ Schan,
                                         int fi, int b, int tid,
                                         __half2* Bc,
                                         float* wPr, float* wPi,
                                         float* wNr, float* wNi,
                                         float* wQr, float* wQi,
                                         float* w5tr, float* w5ti,
                                         float* hfull, int* drevT, float* sred){
    constexpr int Q = 1 << LQ;
    constexpr int N = P5 * Q;
    constexpr int D = TLEN / N;
    constexpr int S1 = P5 / 5;
    constexpr int EPT = (LQ & 1) ? 2 : 4;             // elems/task in final pass
    constexpr int NTASK = N / EPT;
    constexpr int NFP = (NTASK + 511) / 512;
    __half* Mag = reinterpret_cast<__half*>(Bc);      // reuses Bc after final pass

    const double xi_d = 0.35 * exp2(-(double)fi / 6.0);
    const double r_d  = exp2(1.0 / 6.0);
    const double sig_d = xi_d * (r_d - 1.0) / (r_d + 1.0);
    const float xi = (float)xi_d;
    const float centerT = (float)(xi_d * (double)TLEN);
    const float sigT = (float)(sig_d * (double)TLEN);
    int klo = (int)floorf(centerT - 5.0f * sigT); if (klo < 1) klo = 1;
    int khi = (int)ceilf(centerT + 5.0f * sigT);  if (khi > KMAX - 1) khi = KMAX - 1;
    const float inv2s2 = (float)(1.0 / (2.0 * sig_d * sig_d));

    for (int j = tid; j < P5; j += 512){
        double a = TWO_PI * (double)j / (double)P5;
        wPr[j] = (float)cos(a); wPi[j] = (float)sin(a);
        double a2 = TWO_PI * (double)j / (double)N;
        wNr[j] = (float)cos(a2); wNi[j] = (float)sin(a2);
        drevT[j] = (P5 == 125) ? drev125(j) : ((j % 5) * 5 + j / 5);
    }
    for (int j = tid; j < Q; j += 512){
        double a = TWO_PI * (double)j / (double)Q;
        wQr[j] = (float)cos(a); wQi[j] = (float)sin(a);
    }
    for (int j = tid; j < 25; j += 512){
        double a = TWO_PI * (double)(((j / 5) * (j % 5)) % 5) / 5.0;   // e^{+2pi(qr%5)/5}
        w5tr[j] = (float)cos(a); w5ti[j] = (float)sin(a);
    }
    for (int j = tid; j <= 2 * DHALF; j += 512){
        double st = 1.0 / (TWO_PI * (0.35 / 64.0));
        double dd = (double)(j - DHALF);
        hfull[j] = (float)((0.35 / 64.0) * sqrt(TWO_PI) * exp(-0.5 * dd * dd / (st * st)));
    }
    __syncthreads();
    // ---- radix-5 stage 1 over j, FUSED with psi-weighted global init -----
    for (int task = tid; task < S1 * Q; task += 512){
        int m = task >> LQ, k2 = task & (Q - 1);
        float vr[5], vi[5];
        #pragma unroll
        for (int r = 0; r < 5; ++r){
            int gk = k2 + ((m + r * S1) << LQ);
            float ur = 0.0f, ui = 0.0f;
            if (gk >= klo && gk <= khi){
                float fr = (float)gk * (1.0f / (float)TLEN);
                float d = fr - xi;
                float p = __expf(-d * d * inv2s2) * (1.0f / (float)TLEN);
                float2 Xv = Xfb[gk];
                ur = Xv.x * p; ui = Xv.y * p;
            }
            vr[r] = ur; vi[r] = ui;
        }
        int base = m * Q + k2;
        #pragma unroll
        for (int q = 0; q < 5; ++q){
            float cr = vr[0], ci = vi[0];
            #pragma unroll
            for (int r = 1; r < 5; ++r){
                float wr = w5tr[q * 5 + r], wi = w5ti[q * 5 + r];
                cr += vr[r] * wr - vi[r] * wi;
                ci += vr[r] * wi + vi[r] * wr;
            }
            int jt = m * q;                   // f = 1
            float tr = wPr[jt], ti = wPi[jt];
            Bc[base + q * S1 * Q] = pk2(cr * tr - ci * ti, cr * ti + ci * tr);
        }
    }
    // ---- middle radix-5 stage (P5=125 only): s=5, f=5 --------------------
    if (P5 == 125){
        __syncthreads();
        for (int task = tid; task < 25 * Q; task += 512){
            int u = task >> LQ, k2 = task & (Q - 1);
            int blk = u / 5, m = u - blk * 5;
            int base = (blk * 25 + m) * Q + k2;
            float vr[5], vi[5];
            #pragma unroll
            for (int r = 0; r < 5; ++r){
                __half2 v = Bc[base + r * 5 * Q];
                vr[r] = lo2f(v); vi[r] = hi2f(v);
            }
            #pragma unroll
            for (int q = 0; q < 5; ++q){
                float cr = vr[0], ci = vi[0];
                #pragma unroll
                for (int r = 1; r < 5; ++r){
                    float wr = w5tr[q * 5 + r], wi = w5ti[q * 5 + r];
                    cr += vr[r] * wr - vi[r] * wi;
                    ci += vr[r] * wi + vi[r] * wr;
                }
                int jt = m * q * 5;           // < 125
                float tr = wPr[jt], ti = wPi[jt];
                Bc[base + q * 5 * Q] = pk2(cr * tr - ci * ti, cr * ti + ci * tr);
            }
        }
    }
    // ---- final radix-5 stage fused with W_N^{+k2 n1} output twiddle ------
    __syncthreads();
    for (int task = tid; task < S1 * Q; task += 512){
        int u = task >> LQ, k2 = task & (Q - 1);
        int base = (u * 5) * Q + k2;
        float vr[5], vi[5];
        #pragma unroll
        for (int r = 0; r < 5; ++r){
            __half2 v = Bc[base + r * Q];
            vr[r] = lo2f(v); vi[r] = hi2f(v);
        }
        #pragma unroll
        for (int q = 0; q < 5; ++q){
            float cr = vr[0], ci = vi[0];
            #pragma unroll
            for (int r = 1; r < 5; ++r){
                float wr = w5tr[q * 5 + r], wi = w5ti[q * 5 + r];
                cr += vr[r] * wr - vi[r] * wi;
                ci += vr[r] * wi + vi[r] * wr;
            }
            int n1 = drevT[5 * u + q];
            int a = k2 * n1;                  // < N = P5*qq + rr
            int qq = a / P5, rr = a - qq * P5;
            float tr = wQr[qq] * wNr[rr] - wQi[qq] * wNi[rr];
            float ti = wQr[qq] * wNi[rr] + wQi[qq] * wNr[rr];
            Bc[base + q * Q] = pk2(cr * tr - ci * ti, cr * ti + ci * tr);
        }
    }
    // ---- radix-4 passes over k2, EXCEPT the final butterfly level --------
    #pragma unroll
    for (int pass = 0; pass + 1 < LQ / 2 + (LQ & 1); ++pass){
        const int Sp = Q >> (1 + 2 * pass);
        const int half = Sp >> 1;
        __syncthreads();
        for (int task = tid; task < P5 * (Q / 4); task += 512){
            int prow = task / (Q / 4), v = task & (Q / 4 - 1);
            int blkq = v / half, m = v - blkq * half;
            int base = prow * Q + blkq * 2 * Sp + m;
            __half2 vA = Bc[base],        vB = Bc[base + half];
            __half2 vC = Bc[base + Sp],   vD = Bc[base + Sp + half];
            float Ar = lo2f(vA), Ai = hi2f(vA);
            float B2r = lo2f(vB), B2i = hi2f(vB);
            float Cr = lo2f(vC), Ci = hi2f(vC);
            float D2r = lo2f(vD), D2i = hi2f(vD);
            int jt1 = m * ((Q / 2) / Sp);
            float w1r = wQr[jt1], w1i = wQi[jt1];
            float w2r = wQr[2 * jt1], w2i = wQi[2 * jt1];
            float A1r = Ar + Cr, A1i = Ai + Ci;
            float t1r = Ar - Cr, t1i = Ai - Ci;
            float C1r = t1r * w1r - t1i * w1i, C1i = t1r * w1i + t1i * w1r;
            float B1r = B2r + D2r, B1i = B2i + D2i;
            float t2r = B2r - D2r, t2i = B2i - D2i;
            float t3r = -t2i, t3i = t2r;
            float D1r = t3r * w1r - t3i * w1i, D1i = t3r * w1i + t3i * w1r;
            Bc[base] = pk2(A1r + B1r, A1i + B1i);
            float u1r = A1r - B1r, u1i = A1i - B1i;
            Bc[base + half] = pk2(u1r * w2r - u1i * w2i, u1r * w2i + u1i * w2r);
            Bc[base + Sp] = pk2(C1r + D1r, C1i + D1i);
            float u2r = C1r - D1r, u2i = C1i - D1i;
            Bc[base + Sp + half] = pk2(u2r * w2r - u2i * w2i, u2r * w2i + u2i * w2r);
        }
    }
    __syncthreads();
    // ---- FINAL butterfly level fused with |z| (twiddles are exactly 1) ---
    float magf[NFP][EPT];
    #pragma unroll
    for (int i = 0; i < NFP; ++i){
        int task = tid + 512 * i;
        if (task < NTASK){
            if (LQ & 1){                      // leftover span-1 radix-2
                int p = task / (Q / 2), u = task - p * (Q / 2);
                int i0 = p * Q + 2 * u;
                __half2 v0 = Bc[i0], v1 = Bc[i0 + 1];
                float ar = lo2f(v0), ai = hi2f(v0);
                float br2 = lo2f(v1), bi2 = hi2f(v1);
                float o0r = ar + br2, o0i = ai + bi2;
                float o1r = ar - br2, o1i = ai - bi2;
                magf[i][0] = sqrtf(o0r * o0r + o0i * o0i);
                magf[i][1] = sqrtf(o1r * o1r + o1i * o1i);
            } else {                          // final radix-4 (Sp=2, half=1, m=0)
                int prow = task / (Q / 4), v = task & (Q / 4 - 1);
                int base = prow * Q + 4 * v;
                __half2 v0 = Bc[base], v1 = Bc[base + 1];
                __half2 v2 = Bc[base + 2], v3 = Bc[base + 3];
                float Ar = lo2f(v0), Ai = hi2f(v0);
                float B2r = lo2f(v1), B2i = hi2f(v1);
                float Cr = lo2f(v2), Ci = hi2f(v2);
                float D2r = lo2f(v3), D2i = hi2f(v3);
                float A1r = Ar + Cr, A1i = Ai + Ci;
                float C1r = Ar - Cr, C1i = Ai - Ci;
                float B1r = B2r + D2r, B1i = B2i + D2i;
                float t2r = B2r - D2r, t2i = B2i - D2i;
                float D1r = -t2i, D1i = t2r;          // * i (plus sign)
                float o0r = A1r + B1r, o0i = A1i + B1i;
                float o1r = A1r - B1r, o1i = A1i - B1i;
                float o2r = C1r + D1r, o2i = C1i + D1i;
                float o3r = C1r - D1r, o3i = C1i - D1i;
                magf[i][0] = sqrtf(o0r * o0r + o0i * o0i);
                magf[i][1] = sqrtf(o1r * o1r + o1i * o1i);
                magf[i][2] = sqrtf(o2r * o2r + o2i * o2i);
                magf[i][3] = sqrtf(o3r * o3r + o3i * o3i);
            }
        }
    }
    __syncthreads();                          // all final-level reads done
    // ---- scatter mags to padded-linear Mag (aliases Bc): np + (np>>4) ----
    #pragma unroll
    for (int i = 0; i < NFP; ++i){
        int task = tid + 512 * i;
        if (task < NTASK){
            int row, s0;
            if (LQ & 1){ row = task / (Q / 2); s0 = 2 * (task - row * (Q / 2)); }
            else       { row = task / (Q / 4); s0 = 4 * (task & (Q / 4 - 1)); }
            #pragma unroll
            for (int e = 0; e < EPT; ++e){
                int slot = s0 + e;
                int n2 = (int)(__brev((unsigned)slot) >> (32 - LQ));
                int np = drevT[row] + P5 * n2;
                Mag[np + (np >> 4)] = __float2half(magf[i][e]);
            }
        }
    }
    __syncthreads();
    // ---- conv: S1[t] = D * sum_n phi(64t - Dn) Mag[n], 2-way tap split ---
    float acc = 0.0f;
    if (tid < 500){
        int t = tid - 250 * (tid / 250);
        int q = tid / 250;
        int m0 = 64 * t;
        int lo = m0 - DHALF;
        int nlo = (lo >= 0) ? ((lo + D - 1) / D) : -((-lo) / D);
        int nhi = (m0 + DHALF) / D;
        int n = nlo + q;
        if (n <= nhi){
            int np = n % N; if (np < 0) np += N;
            int d = m0 - D * n + DHALF;
            for (; n <= nhi; n += 2){
                acc += hfull[d] * __half2float(Mag[np + (np >> 4)]);
                d -= 2 * D;
                np += 2; if (np >= N) np -= N;
            }
        }
        sred[tid] = acc;
    }
    __syncthreads();
    if (tid < 250)
        Schan[(b * NCH + 1 + fi) * NOUT + tid] = (sred[tid] + sred[tid + 250]) * (float)D;
}

// ---- K2: all 36 channels + S0 in one 2368-block dispatch (512 thr) -------
// LDS ~39.5 KB -> 4 blocks/CU; complex as __half2 = 1 LDS op per access.
__global__ __launch_bounds__(512, 4) void k_env_all(const float* __restrict__ x,
                                                    const float2* __restrict__ Xf,
                                                    float* __restrict__ Schan){
    __shared__ __half2 Bc[8000];               // complex plane; Mag aliases it
    __shared__ float wPr[125], wPi[125];
    __shared__ float wNr[125], wNi[125];
    __shared__ float wQr[128], wQi[128];
    __shared__ float w5tr[25], w5ti[25];
    __shared__ float hfull[2 * DHALF + 1];
    __shared__ int   drevT[125];
    __shared__ float sred[500];

    const int bi = blockIdx.x;
    const int tid = threadIdx.x;
    if (bi < 448){                         // N=8000, D=2,  fi 0-6
        int fi = bi >> 6, b = bi & 63;
        env_body<125, 6>(Xf + (size_t)b * KMAX, Schan, fi, b, tid, Bc,
                         wPr, wPi, wNr, wNi, wQr, wQi, w5tr, w5ti, hfull, drevT, sred);
    } else if (bi < 640){                  // N=4000, D=4,  fi 7-9
        int t = bi - 448;
        int fi = 7 + (t >> 6), b = t & 63;
        env_body<125, 5>(Xf + (size_t)b * KMAX, Schan, fi, b, tid, Bc,
                         wPr, wPi, wNr, wNi, wQr, wQi, w5tr, w5ti, hfull, drevT, sred);
    } else if (bi < 1088){                 // N=3200, D=5,  fi 10-16
        int t = bi - 640;
        int fi = 10 + (t >> 6), b = t & 63;
        env_body<25, 7>(Xf + (size_t)b * KMAX, Schan, fi, b, tid, Bc,
                        wPr, wPi, wNr, wNi, wQr, wQi, w5tr, w5ti, hfull, drevT, sred);
    } else if (bi < 1408){                 // N=2000, D=8,  fi 17-21
        int t = bi - 1088;
        int fi = 17 + (t >> 6), b = t & 63;
        env_body<125, 4>(Xf + (size_t)b * KMAX, Schan, fi, b, tid, Bc,
                         wPr, wPi, wNr, wNi, wQr, wQi, w5tr, w5ti, hfull, drevT, sred);
    } else if (bi < 2304){                 // N=1600, D=10, fi 22-35
        int t = bi - 1408;
        int fi = 22 + (t >> 6), b = t & 63;
        env_body<25, 6>(Xf + (size_t)b * KMAX, Schan, fi, b, tid, Bc,
                        wPr, wPi, wNr, wNi, wQr, wQi, w5tr, w5ti, hfull, drevT, sred);
    } else {                               // S0 channel, one block per batch
        int b = bi - 2304;
        const float* xb = x + (size_t)b * TLEN;
        for (int j = tid; j <= 2 * DHALF; j += 512){
            double st = 1.0 / (TWO_PI * (0.35 / 64.0));
            double dd = (double)(j - DHALF);
            hfull[j] = (float)((0.35 / 64.0) * sqrt(TWO_PI) * exp(-0.5 * dd * dd / (st * st)));
        }
        __syncthreads();
        float acc = 0.0f;
        if (tid < 500){
            int t = tid - 250 * (tid / 250);
            int q = tid / 250;
            int m0 = 64 * t;
            for (int j = q; j <= 2 * DHALF; j += 2){
                int n = m0 - DHALF + j;
                if (n < 0) n += TLEN; else if (n >= TLEN) n -= TLEN;
                acc += hfull[j] * xb[n];
            }
            sred[tid] = acc;
        }
        __syncthreads();
        if (tid < 250)
            Schan[(b * NCH + 0) * NOUT + tid] = sred[tid] + sred[tid + 250];
    }
}

// ---- K4: channel-group means -> f32 --------------------------------------
__global__ __launch_bounds__(256) void k_reduce(const float* __restrict__ Schan,
                                                float* __restrict__ out){
    int o = blockIdx.x * 256 + threadIdx.x;
    if (o >= NBATCH * 3 * NOUT) return;
    int b = o / (3 * NOUT);
    int rem = o - b * 3 * NOUT;
    int g = rem / NOUT;
    int t = rem - g * NOUT;
    int c0 = (g == 0) ? 0 : (g == 1 ? 12 : 24);
    int c1 = (g == 0) ? 12 : (g == 1 ? 24 : 37);
    float s = 0.0f;
    for (int c = c0; c < c1; ++c) s += Schan[(b * NCH + c) * NOUT + t];
    out[o] = s / (float)(c1 - c0);
}

__global__ void k_fill_f32(float* out, int n, float v){
    int i = blockIdx.x * 256 + threadIdx.x;
    if (i < n) out[i] = v;
}

extern "C" void kernel_launch(void* const* d_in, const int* in_sizes, int n_in,
                              void* d_out, int out_size, void* d_ws, size_t ws_size,
                              hipStream_t stream) {
    const float* x = (const float*)d_in[0];
    float* out = (float*)d_out;
    const size_t xf_bytes = (size_t)NBATCH * KMAX * sizeof(float2);          // 4.10 MB
    const size_t schan_bytes = (size_t)NBATCH * NCH * NOUT * sizeof(float);  // 2.37 MB
    const size_t gtmp_bytes = (size_t)NBATCH * 16000 * sizeof(float2);       // 8.19 MB
    if (ws_size < xf_bytes + schan_bytes + gtmp_bytes){
        k_fill_f32<<<(out_size + 255) / 256, 256, 0, stream>>>(out, out_size, 800.0f);
        return;
    }
    float2* Xf = (float2*)d_ws;
    float* Schan = (float*)((char*)d_ws + xf_bytes);
    float2* Gtmp = (float2*)((char*)d_ws + xf_bytes + schan_bytes);

    k_ffta<<<NBATCH * 8, 256, 0, stream>>>(x, Gtmp);
    k_fftb<<<NBATCH * 25, 128, 0, stream>>>(Gtmp, Xf);
    k_env_all<<<2368, 512, 0, stream>>>(x, Xf, Schan);
    k_reduce<<<(NBATCH * 3 * NOUT + 255) / 256, 256, 0, stream>>>(Schan, out);
}